// Round 1
// baseline (330.336 us; speedup 1.0000x reference)
//
#include <hip/hip_runtime.h>

typedef unsigned short u16;
typedef __attribute__((ext_vector_type(4))) float f32x4;
typedef __attribute__((ext_vector_type(8))) __bf16 bf16x8;
typedef __attribute__((ext_vector_type(4))) u16 u16x4;

// ---------- helpers ----------

__device__ __forceinline__ u16 f2bf(float f) {
  union { float f; unsigned u; } v; v.f = f;
  unsigned r = v.u + 0x7fffu + ((v.u >> 16) & 1u);
  return (u16)(r >> 16);
}

__device__ __forceinline__ void stage16(const void* g, void* l) {
#if __has_builtin(__builtin_amdgcn_global_load_lds)
  __builtin_amdgcn_global_load_lds((const __attribute__((address_space(1))) void*)g,
                                   (__attribute__((address_space(3))) void*)l, 16, 0, 0);
#else
  *(f32x4*)l = *(const f32x4*)g;
#endif
}

__device__ __forceinline__ f32x4 mfma16(bf16x8 a, bf16x8 b, f32x4 c) {
  return __builtin_amdgcn_mfma_f32_16x16x32_bf16(a, b, c, 0, 0, 0);
}

// rope channel select: sections [16,24,24,16,24,24] -> channels 0,1,2,0,1,2
__device__ __forceinline__ int rope_ch(int d) {
  int dd = (d < 64) ? d : d - 64;
  return (dd < 16) ? 0 : (dd < 40 ? 1 : 2);
}

// ---------- kernels ----------

// fp32 -> bf16, vectorized; n4 = element count / 4
__global__ void yuna_convert_bf16(const float* __restrict__ in, u16* __restrict__ out, int n4) {
  int i = blockIdx.x * blockDim.x + threadIdx.x;
  if (i < n4) {
    f32x4 v = ((const f32x4*)in)[i];
    u16x4 o;
    o.x = f2bf(v.x); o.y = f2bf(v.y); o.z = f2bf(v.z); o.w = f2bf(v.w);
    ((u16x4*)out)[i] = o;
  }
}

// out[n][k] = bf16(W[k][n]); K = gridDim.x*64 (=2048 here), ldo = 2048
__global__ void yuna_transpose_bf16(const float* __restrict__ W, u16* __restrict__ out, int N) {
  __shared__ float tile[64][65];
  int k0 = blockIdx.x * 64, n0 = blockIdx.y * 64;
  int tx = threadIdx.x & 63, ty = threadIdx.x >> 6;  // tx 0..63, ty 0..3
#pragma unroll
  for (int j = 0; j < 64; j += 4)
    tile[ty + j][tx] = W[(size_t)(k0 + ty + j) * N + n0 + tx];
  __syncthreads();
#pragma unroll
  for (int j = 0; j < 64; j += 4)
    out[(size_t)(n0 + ty + j) * 2048 + k0 + tx] = f2bf(tile[tx][ty + j]);
}

// C[M][N] fp32 = A[M][K] bf16 @ Bt[N][K] bf16.  128x128 tile, BK=64.
__global__ __launch_bounds__(256, 2) void yuna_gemm_bt(
    const u16* __restrict__ A, const u16* __restrict__ Bt,
    float* __restrict__ C, int M, int N, int K) {
  __shared__ __align__(16) u16 As[128 * 64];
  __shared__ __align__(16) u16 Bs[128 * 64];
  const int tid = threadIdx.x;
  const int wave = tid >> 6, lane = tid & 63;
  const int m0 = blockIdx.x * 128, n0 = blockIdx.y * 128;
  const int wr = (wave >> 1) * 64, wc = (wave & 1) * 64;
  const int lrow = lane & 15, lkg = lane >> 4;

  const f32x4 fzero = {0.f, 0.f, 0.f, 0.f};
  f32x4 acc[4][4];
#pragma unroll
  for (int mi = 0; mi < 4; ++mi)
#pragma unroll
    for (int ni = 0; ni < 4; ++ni) acc[mi][ni] = fzero;

  for (int k0 = 0; k0 < K; k0 += 64) {
    __syncthreads();
#pragma unroll
    for (int it = 0; it < 4; ++it) {
      int chunk = tid + it * 256;     // 16B chunk index 0..1023
      int row = chunk >> 3;           // 8 chunks per 128B row
      int ce = (chunk & 7) * 8;       // element offset within row
      stage16(A + (size_t)(m0 + row) * K + k0 + ce, (char*)As + chunk * 16);
      stage16(Bt + (size_t)(n0 + row) * K + k0 + ce, (char*)Bs + chunk * 16);
    }
    asm volatile("s_waitcnt vmcnt(0)" ::: "memory");
    __syncthreads();
#pragma unroll
    for (int kk = 0; kk < 2; ++kk) {
      int kb = kk * 64 + lkg * 16;    // byte offset within 128B row
      bf16x8 af[4], bfr[4];
#pragma unroll
      for (int mi = 0; mi < 4; ++mi)
        af[mi] = *(const bf16x8*)((const char*)As + (wr + mi * 16 + lrow) * 128 + kb);
#pragma unroll
      for (int ni = 0; ni < 4; ++ni)
        bfr[ni] = *(const bf16x8*)((const char*)Bs + (wc + ni * 16 + lrow) * 128 + kb);
#pragma unroll
      for (int mi = 0; mi < 4; ++mi)
#pragma unroll
        for (int ni = 0; ni < 4; ++ni)
          acc[mi][ni] = mfma16(af[mi], bfr[ni], acc[mi][ni]);
    }
  }
  // epilogue: C/D layout col=lane&15, row=(lane>>4)*4+reg
#pragma unroll
  for (int mi = 0; mi < 4; ++mi)
#pragma unroll
    for (int ni = 0; ni < 4; ++ni) {
      int r0 = m0 + wr + mi * 16 + lkg * 4;
      int c = n0 + wc + ni * 16 + lrow;
#pragma unroll
      for (int r = 0; r < 4; ++r)
        C[(size_t)(r0 + r) * N + c] = acc[mi][ni][r];
    }
}

// bias + multi-section rope + scatter.
// qkv [2048][3072] fp32 (raw x@W).  Writes:
//  qb  bf16 [16][2048][128]  (pre-scaled by 1/sqrt(128)*log2e)
//  kb  bf16 [4][2048][128], pk fp32 [4][2048][128]
//  vtb bf16 [4][128][2048] (transposed), pv fp32 [4][2048][128]
__global__ void yuna_rope_scatter(
    const float* __restrict__ qkv, const float* __restrict__ bq,
    const float* __restrict__ bk, const float* __restrict__ bv,
    const float* __restrict__ cosp, const float* __restrict__ sinp,
    u16* __restrict__ qb, u16* __restrict__ kb, u16* __restrict__ vtb,
    float* __restrict__ pk, float* __restrict__ pv) {
  const float QSCALE = 1.4426950408889634f * 0.08838834764831845f;
  int t = blockIdx.x;
  int tid = threadIdx.x;
  const float* row = qkv + (size_t)t * 3072;
  // q: 16 heads x 64 pairs
  for (int i = tid; i < 1024; i += 256) {
    int h = i >> 6, d = i & 63;
    float a = row[h * 128 + d] + bq[h * 128 + d];
    float b = row[h * 128 + d + 64] + bq[h * 128 + d + 64];
    size_t cbase = (size_t)t * 128;
    float c0 = cosp[(size_t)rope_ch(d) * 262144 + cbase + d];
    float s0 = sinp[(size_t)rope_ch(d) * 262144 + cbase + d];
    float c1 = cosp[(size_t)rope_ch(d + 64) * 262144 + cbase + d + 64];
    float s1 = sinp[(size_t)rope_ch(d + 64) * 262144 + cbase + d + 64];
    float o0 = a * c0 - b * s0;
    float o1 = b * c1 + a * s1;
    size_t o = ((size_t)h * 2048 + t) * 128 + d;
    qb[o] = f2bf(o0 * QSCALE);
    qb[o + 64] = f2bf(o1 * QSCALE);
  }
  // k: 4 kv heads x 64 pairs (one pass)
  {
    int i = tid;
    int kvh = i >> 6, d = i & 63;
    float a = row[2048 + kvh * 128 + d] + bk[kvh * 128 + d];
    float b = row[2048 + kvh * 128 + d + 64] + bk[kvh * 128 + d + 64];
    size_t cbase = (size_t)t * 128;
    float c0 = cosp[(size_t)rope_ch(d) * 262144 + cbase + d];
    float s0 = sinp[(size_t)rope_ch(d) * 262144 + cbase + d];
    float c1 = cosp[(size_t)rope_ch(d + 64) * 262144 + cbase + d + 64];
    float s1 = sinp[(size_t)rope_ch(d + 64) * 262144 + cbase + d + 64];
    float o0 = a * c0 - b * s0;
    float o1 = b * c1 + a * s1;
    size_t o = ((size_t)kvh * 2048 + t) * 128 + d;
    kb[o] = f2bf(o0); kb[o + 64] = f2bf(o1);
    pk[o] = o0; pk[o + 64] = o1;
  }
  // v: 4 kv heads x 128
  for (int i = tid; i < 512; i += 256) {
    int kvh = i >> 7, d = i & 127;
    float val = row[2560 + kvh * 128 + d] + bv[kvh * 128 + d];
    pv[((size_t)kvh * 2048 + t) * 128 + d] = val;
    vtb[((size_t)kvh * 128 + d) * 2048 + t] = f2bf(val);
  }
}

// flash attention, causal, GQA 16q/4kv.  BM=64 (16/wave), BN=128.
// Q pre-scaled by 1/sqrt(128)*log2e; softmax in exp2 domain.
__global__ __launch_bounds__(256, 2) void yuna_flash_attn(
    const u16* __restrict__ Q,   // [16][2048][128]
    const u16* __restrict__ Kb,  // [4][2048][128]
    const u16* __restrict__ Vt,  // [4][128][2048]
    u16* __restrict__ Y) {       // [2048][2048] bf16 (t-major, heads concat)
  __shared__ __align__(16) u16 Ks[128 * 128];
  __shared__ __align__(16) u16 Vs[128 * 128];
  __shared__ __align__(16) u16 Ps[4][16 * 128];
  const int h = blockIdx.x;
  const int yb = blockIdx.y;
  // balance: block b pairs with b+256 -> qb sums to 31 (17 iters/CU)
  const int qb = (yb < 16) ? (2 * yb) : (63 - 2 * yb);
  const int kvh = h >> 2;
  const int tid = threadIdx.x, wave = tid >> 6, lane = tid & 63;
  const int lrow = lane & 15, lkg = lane >> 4;
  const int t0 = qb * 64;
  const int rw0 = t0 + wave * 16;

  // Q fragments (A layout: m=lane&15, k=quad*8+j), held for whole block
  bf16x8 qf[4];
  const u16* qrow = Q + ((size_t)h * 2048 + rw0 + lrow) * 128;
#pragma unroll
  for (int kk = 0; kk < 4; ++kk)
    qf[kk] = *(const bf16x8*)(qrow + kk * 32 + lkg * 8);

  const f32x4 fzero = {0.f, 0.f, 0.f, 0.f};
  f32x4 o[8];
#pragma unroll
  for (int dt = 0; dt < 8; ++dt) o[dt] = fzero;
  float m_i[4], l_i[4];
#pragma unroll
  for (int r = 0; r < 4; ++r) { m_i[r] = -1e30f; l_i[r] = 0.f; }

  const int nkb = (t0 + 63) / 128 + 1;
  for (int kb = 0; kb < nkb; ++kb) {
    __syncthreads();
#pragma unroll
    for (int it = 0; it < 8; ++it) {
      int chunk = tid + it * 256;  // 0..2047
      int row = chunk >> 4;        // 16 chunks per 256B row
      int ce = (chunk & 15) * 8;
      stage16(Kb + ((size_t)kvh * 2048 + kb * 128 + row) * 128 + ce, (char*)Ks + chunk * 16);
      stage16(Vt + ((size_t)kvh * 128 + row) * 2048 + (size_t)kb * 128 + ce, (char*)Vs + chunk * 16);
    }
    asm volatile("s_waitcnt vmcnt(0)" ::: "memory");
    __syncthreads();

    // S = Q @ K^T   (B frag: K natural layout, contiguous in d)
    f32x4 s[8];
#pragma unroll
    for (int nt = 0; nt < 8; ++nt) s[nt] = fzero;
#pragma unroll
    for (int kk = 0; kk < 4; ++kk) {
#pragma unroll
      for (int nt = 0; nt < 8; ++nt) {
        bf16x8 bk = *(const bf16x8*)((const char*)Ks + (nt * 16 + lrow) * 256 + kk * 64 + lkg * 16);
        s[nt] = mfma16(qf[kk], bk, s[nt]);
      }
    }
    // causal mask (only diagonal blocks trigger)
    if (kb * 128 + 127 > rw0) {
#pragma unroll
      for (int nt = 0; nt < 8; ++nt) {
        int col = kb * 128 + nt * 16 + lrow;
#pragma unroll
        for (int r = 0; r < 4; ++r) {
          int rowi = rw0 + lkg * 4 + r;
          if (col > rowi) s[nt][r] = -1e30f;
        }
      }
    }
    // online softmax (rows live in 16-lane groups; butterfly over low 4 bits)
#pragma unroll
    for (int r = 0; r < 4; ++r) {
      float mx = s[0][r];
#pragma unroll
      for (int nt = 1; nt < 8; ++nt) mx = fmaxf(mx, s[nt][r]);
      mx = fmaxf(mx, __shfl_xor(mx, 1, 64));
      mx = fmaxf(mx, __shfl_xor(mx, 2, 64));
      mx = fmaxf(mx, __shfl_xor(mx, 4, 64));
      mx = fmaxf(mx, __shfl_xor(mx, 8, 64));
      float mnew = fmaxf(m_i[r], mx);
      float alpha = exp2f(m_i[r] - mnew);
      m_i[r] = mnew;
      float ps = 0.f;
#pragma unroll
      for (int nt = 0; nt < 8; ++nt) {
        float p = exp2f(s[nt][r] - mnew);
        s[nt][r] = p;
        ps += p;
      }
      ps += __shfl_xor(ps, 1, 64);
      ps += __shfl_xor(ps, 2, 64);
      ps += __shfl_xor(ps, 4, 64);
      ps += __shfl_xor(ps, 8, 64);
      l_i[r] = l_i[r] * alpha + ps;
#pragma unroll
      for (int dt = 0; dt < 8; ++dt) o[dt][r] *= alpha;
      // P: C layout -> LDS (wave-private)
      u16* pr = &Ps[wave][(lkg * 4 + r) * 128];
#pragma unroll
      for (int nt = 0; nt < 8; ++nt) pr[nt * 16 + lrow] = f2bf(s[nt][r]);
    }
    // O += P @ V   (A frag from Ps; B frag from V^T tile, contiguous in t)
#pragma unroll
    for (int kk = 0; kk < 4; ++kk) {
      bf16x8 pa = *(const bf16x8*)(&Ps[wave][lrow * 128 + kk * 32 + lkg * 8]);
#pragma unroll
      for (int dt = 0; dt < 8; ++dt) {
        bf16x8 bv = *(const bf16x8*)((const char*)Vs + (dt * 16 + lrow) * 256 + kk * 64 + lkg * 16);
        o[dt] = mfma16(pa, bv, o[dt]);
      }
    }
  }
  // write y_attn[t][h*128+d] bf16
#pragma unroll
  for (int r = 0; r < 4; ++r) {
    float inv = 1.f / l_i[r];
    int rowi = rw0 + lkg * 4 + r;
#pragma unroll
    for (int dt = 0; dt < 8; ++dt)
      Y[(size_t)rowi * 2048 + h * 128 + dt * 16 + lrow] = f2bf(o[dt][r] * inv);
  }
}

// ---------- launch ----------

extern "C" void kernel_launch(void* const* d_in, const int* in_sizes, int n_in,
                              void* d_out, int out_size, void* d_ws, size_t ws_size,
                              hipStream_t stream) {
  const float* x = (const float*)d_in[0];
  const float* cosp = (const float*)d_in[1];
  const float* sinp = (const float*)d_in[2];
  const float* Wq = (const float*)d_in[3];
  const float* bq = (const float*)d_in[4];
  const float* Wk = (const float*)d_in[5];
  const float* bk = (const float*)d_in[6];
  const float* Wv = (const float*)d_in[7];
  const float* bv = (const float*)d_in[8];
  const float* Wo = (const float*)d_in[9];
  float* out = (float*)d_out;
  float* out_k = out + 4194304;
  float* out_v = out + 5242880;

  char* ws = (char*)d_ws;
  u16* xb   = (u16*)(ws + 0);          //  8 MB  x  bf16 [2048][2048]
  u16* Wb   = (u16*)(ws + 8388608);    // 12 MB  fused W^T bf16 [3072][2048]
  u16* Wob  = (u16*)(ws + 20971520);   //  8 MB  Wo^T bf16 [2048][2048]
  float* qkv = (float*)(ws + 29360128);// 24 MB  raw qkv fp32 [2048][3072]
  u16* qbuf = (u16*)(ws + 54525952);   //  8 MB  q bf16 [16][2048][128]
  u16* kbuf = (u16*)(ws + 62914560);   //  2 MB  k bf16 [4][2048][128]
  u16* vtb  = (u16*)(ws + 65011712);   //  2 MB  v^T bf16 [4][128][2048]
  u16* yat  = (u16*)(ws + 67108864);   //  8 MB  attn out bf16 [2048][2048]

  yuna_convert_bf16<<<4096, 256, 0, stream>>>(x, xb, 1048576);
  yuna_transpose_bf16<<<dim3(32, 32), 256, 0, stream>>>(Wq, Wb, 2048);
  yuna_transpose_bf16<<<dim3(32, 8), 256, 0, stream>>>(Wk, Wb + (size_t)2048 * 2048, 512);
  yuna_transpose_bf16<<<dim3(32, 8), 256, 0, stream>>>(Wv, Wb + (size_t)2560 * 2048, 512);
  yuna_transpose_bf16<<<dim3(32, 32), 256, 0, stream>>>(Wo, Wob, 2048);
  yuna_gemm_bt<<<dim3(16, 24), 256, 0, stream>>>(xb, Wb, qkv, 2048, 3072, 2048);
  yuna_rope_scatter<<<2048, 256, 0, stream>>>(qkv, bq, bk, bv, cosp, sinp,
                                              qbuf, kbuf, vtb, out_k, out_v);
  yuna_flash_attn<<<dim3(16, 32), 256, 0, stream>>>(qbuf, kbuf, vtb, yat);
  yuna_gemm_bt<<<dim3(16, 16), 256, 0, stream>>>(yat, Wob, out, 2048, 2048, 2048);
}

// Round 2
// 270.447 us; speedup vs baseline: 1.2214x; 1.2214x over previous
//
#include <hip/hip_runtime.h>

typedef unsigned short u16;
typedef __attribute__((ext_vector_type(4))) float f32x4;
typedef __attribute__((ext_vector_type(8))) __bf16 bf16x8;
typedef __attribute__((ext_vector_type(4))) u16 u16x4;

// ---------- helpers ----------

__device__ __forceinline__ u16 f2bf(float f) {
  union { float f; unsigned u; } v; v.f = f;
  unsigned r = v.u + 0x7fffu + ((v.u >> 16) & 1u);
  return (u16)(r >> 16);
}

__device__ __forceinline__ void stage16(const void* g, void* l) {
#if __has_builtin(__builtin_amdgcn_global_load_lds)
  __builtin_amdgcn_global_load_lds((const __attribute__((address_space(1))) void*)g,
                                   (__attribute__((address_space(3))) void*)l, 16, 0, 0);
#else
  *(f32x4*)l = *(const f32x4*)g;
#endif
}

__device__ __forceinline__ f32x4 mfma16(bf16x8 a, bf16x8 b, f32x4 c) {
  return __builtin_amdgcn_mfma_f32_16x16x32_bf16(a, b, c, 0, 0, 0);
}

__device__ __forceinline__ float fexp2(float x) {
#if __has_builtin(__builtin_amdgcn_exp2f)
  return __builtin_amdgcn_exp2f(x);
#else
  return exp2f(x);
#endif
}

// rope channel select: sections [16,24,24,16,24,24] -> channels 0,1,2,0,1,2
__device__ __forceinline__ int rope_ch(int d) {
  int dd = (d < 64) ? d : d - 64;
  return (dd < 16) ? 0 : (dd < 40 ? 1 : 2);
}

// ---------- kernels ----------

__global__ void yuna_convert_bf16(const float* __restrict__ in, u16* __restrict__ out, int n4) {
  int i = blockIdx.x * blockDim.x + threadIdx.x;
  if (i < n4) {
    f32x4 v = ((const f32x4*)in)[i];
    u16x4 o;
    o.x = f2bf(v.x); o.y = f2bf(v.y); o.z = f2bf(v.z); o.w = f2bf(v.w);
    ((u16x4*)out)[i] = o;
  }
}

// out[n][k] = bf16(W[k][n]); ldo = 2048
__global__ void yuna_transpose_bf16(const float* __restrict__ W, u16* __restrict__ out, int N) {
  __shared__ float tile[64][65];
  int k0 = blockIdx.x * 64, n0 = blockIdx.y * 64;
  int tx = threadIdx.x & 63, ty = threadIdx.x >> 6;
#pragma unroll
  for (int j = 0; j < 64; j += 4)
    tile[ty + j][tx] = W[(size_t)(k0 + ty + j) * N + n0 + tx];
  __syncthreads();
#pragma unroll
  for (int j = 0; j < 64; j += 4)
    out[(size_t)(n0 + ty + j) * 2048 + k0 + tx] = f2bf(tile[tx][ty + j]);
}

// vtb[kvh][d][t] = bf16(pv[kvh][t][d])
__global__ void yuna_transpose_v(const float* __restrict__ pv, u16* __restrict__ vtb) {
  __shared__ float tile[64][65];
  int t0 = blockIdx.x * 64, d0 = blockIdx.y * 64, kvh = blockIdx.z;
  int tx = threadIdx.x & 63, ty = threadIdx.x >> 6;
#pragma unroll
  for (int j = 0; j < 64; j += 4)
    tile[ty + j][tx] = pv[(size_t)(kvh * 2048 + t0 + ty + j) * 128 + d0 + tx];
  __syncthreads();
#pragma unroll
  for (int j = 0; j < 64; j += 4)
    vtb[(size_t)(kvh * 128 + d0 + ty + j) * 2048 + t0 + tx] = f2bf(tile[tx][ty + j]);
}

// C[M][N] fp32 = A[M][K] bf16 @ Bt[N][K] bf16.  Tile 128 x (2*WN), BK=64.
// XOR-swizzled 16B chunks: LDS(row,c) holds global (row, c^(row&7)).
template <int WN>
__global__ __launch_bounds__(256, 2) void yuna_gemm_bt(
    const u16* __restrict__ A, const u16* __restrict__ Bt,
    float* __restrict__ C, int M, int N, int K) {
  constexpr int NF = WN / 16;          // n-frags per wave
  constexpr int BROWS = 2 * WN;        // B tile rows
  __shared__ __align__(16) u16 As[128 * 64];
  __shared__ __align__(16) u16 Bs[BROWS * 64];
  const int tid = threadIdx.x;
  const int wave = tid >> 6, lane = tid & 63;
  const int m0 = blockIdx.x * 128, n0 = blockIdx.y * (2 * WN);
  const int wr = (wave >> 1) * 64, wc = (wave & 1) * WN;
  const int lrow = lane & 15, lkg = lane >> 4;

  // staging constants (swizzle is it-invariant: it*32 rows == 0 mod 8)
  const int srow = tid >> 3;           // base row step 32/iter
  const int ssc = (tid & 7) ^ ((tid >> 3) & 7);
  const size_t abase = (size_t)(m0 + srow) * K + ssc * 8;
  const size_t bbase = (size_t)(n0 + srow) * K + ssc * 8;

  const f32x4 fzero = {0.f, 0.f, 0.f, 0.f};
  f32x4 acc[4][NF];
#pragma unroll
  for (int mi = 0; mi < 4; ++mi)
#pragma unroll
    for (int ni = 0; ni < NF; ++ni) acc[mi][ni] = fzero;

  const int sw = lrow & 7;
  for (int k0 = 0; k0 < K; k0 += 64) {
    __syncthreads();
#pragma unroll
    for (int it = 0; it < 4; ++it)
      stage16(A + abase + (size_t)it * 32 * K + k0, (char*)As + (tid + it * 256) * 16);
#pragma unroll
    for (int it = 0; it < BROWS / 32; ++it)
      stage16(Bt + bbase + (size_t)it * 32 * K + k0, (char*)Bs + (tid + it * 256) * 16);
    asm volatile("s_waitcnt vmcnt(0)" ::: "memory");
    __syncthreads();
#pragma unroll
    for (int kk = 0; kk < 2; ++kk) {
      const int cof = ((kk * 4 + lkg) ^ sw) << 4;
      bf16x8 af[4], bfr[NF];
#pragma unroll
      for (int mi = 0; mi < 4; ++mi)
        af[mi] = *(const bf16x8*)((const char*)As + (wr + mi * 16 + lrow) * 128 + cof);
#pragma unroll
      for (int ni = 0; ni < NF; ++ni)
        bfr[ni] = *(const bf16x8*)((const char*)Bs + (wc + ni * 16 + lrow) * 128 + cof);
#pragma unroll
      for (int mi = 0; mi < 4; ++mi)
#pragma unroll
        for (int ni = 0; ni < NF; ++ni)
          acc[mi][ni] = mfma16(af[mi], bfr[ni], acc[mi][ni]);
    }
  }
#pragma unroll
  for (int mi = 0; mi < 4; ++mi)
#pragma unroll
    for (int ni = 0; ni < NF; ++ni) {
      int r0 = m0 + wr + mi * 16 + lkg * 4;
      int c = n0 + wc + ni * 16 + lrow;
#pragma unroll
      for (int r = 0; r < 4; ++r)
        C[(size_t)(r0 + r) * N + c] = acc[mi][ni][r];
    }
}

// bias + multi-section rope + scatter (V transpose moved to its own kernel)
__global__ void yuna_rope_scatter(
    const float* __restrict__ qkv, const float* __restrict__ bq,
    const float* __restrict__ bk, const float* __restrict__ bv,
    const float* __restrict__ cosp, const float* __restrict__ sinp,
    u16* __restrict__ qb, u16* __restrict__ kb,
    float* __restrict__ pk, float* __restrict__ pv) {
  const float QSCALE = 1.4426950408889634f * 0.08838834764831845f;
  int t = blockIdx.x;
  int tid = threadIdx.x;
  const float* row = qkv + (size_t)t * 3072;
  size_t cbase = (size_t)t * 128;
  for (int i = tid; i < 1024; i += 256) {
    int h = i >> 6, d = i & 63;
    float a = row[h * 128 + d] + bq[h * 128 + d];
    float b = row[h * 128 + d + 64] + bq[h * 128 + d + 64];
    float c0 = cosp[(size_t)rope_ch(d) * 262144 + cbase + d];
    float s0 = sinp[(size_t)rope_ch(d) * 262144 + cbase + d];
    float c1 = cosp[(size_t)rope_ch(d + 64) * 262144 + cbase + d + 64];
    float s1 = sinp[(size_t)rope_ch(d + 64) * 262144 + cbase + d + 64];
    float o0 = a * c0 - b * s0;
    float o1 = b * c1 + a * s1;
    size_t o = ((size_t)h * 2048 + t) * 128 + d;
    qb[o] = f2bf(o0 * QSCALE);
    qb[o + 64] = f2bf(o1 * QSCALE);
  }
  {
    int kvh = tid >> 6, d = tid & 63;
    float a = row[2048 + kvh * 128 + d] + bk[kvh * 128 + d];
    float b = row[2048 + kvh * 128 + d + 64] + bk[kvh * 128 + d + 64];
    float c0 = cosp[(size_t)rope_ch(d) * 262144 + cbase + d];
    float s0 = sinp[(size_t)rope_ch(d) * 262144 + cbase + d];
    float c1 = cosp[(size_t)rope_ch(d + 64) * 262144 + cbase + d + 64];
    float s1 = sinp[(size_t)rope_ch(d + 64) * 262144 + cbase + d + 64];
    float o0 = a * c0 - b * s0;
    float o1 = b * c1 + a * s1;
    size_t o = ((size_t)kvh * 2048 + t) * 128 + d;
    kb[o] = f2bf(o0); kb[o + 64] = f2bf(o1);
    pk[o] = o0; pk[o + 64] = o1;
  }
  for (int i = tid; i < 512; i += 256) {
    int kvh = i >> 7, d = i & 127;
    pv[((size_t)kvh * 2048 + t) * 128 + d] = row[2560 + kvh * 128 + d] + bv[kvh * 128 + d];
  }
}

// flash attention, causal, GQA.  S^T formulation.
// block = 2 waves (128 thr), each wave owns 32 q-rows (2 m-tiles); BN=64.
// Ks[64 n][128 d] swizzled, reused as P[64 m][64 n] and as O staging.
// Vs[128 d][64 n] swizzled.
__global__ __launch_bounds__(128, 2) void yuna_flash_attn(
    const u16* __restrict__ Q,   // [16][2048][128] pre-scaled
    const u16* __restrict__ Kb,  // [4][2048][128]
    const u16* __restrict__ Vt,  // [4][128][2048]
    u16* __restrict__ Y) {       // [2048][2048]
  __shared__ __align__(16) u16 Ks[64 * 128];
  __shared__ __align__(16) u16 Vs[128 * 64];
  const int h = blockIdx.x;
  const int yb = blockIdx.y;
  const int qb = (yb & 1) ? (31 - (yb >> 1)) : (yb >> 1);  // big/small pairing
  const int kvh = h >> 2;
  const int tid = threadIdx.x, wave = tid >> 6, lane = tid & 63;
  const int lrow = lane & 15, lkg = lane >> 4;
  const int mloc0 = wave * 32;
  const int sw = lrow & 7;

  // staging constants
  const int krow = tid >> 4;                       // +8/iter
  const int ksc = (tid & 15) ^ ((tid >> 4) & 7);
  const size_t kbase0 = ((size_t)(kvh * 2048 + krow) << 7) + ksc * 8;
  const int vrow = tid >> 3;                       // +16/iter
  const int vsc = (tid & 7) ^ ((tid >> 3) & 7);
  const size_t vbase0 = (size_t)(kvh * 128 + vrow) * 2048 + vsc * 8;

  // Q fragments: qf[mt][kk]
  bf16x8 qf[2][4];
#pragma unroll
  for (int mt = 0; mt < 2; ++mt)
#pragma unroll
    for (int kk = 0; kk < 4; ++kk)
      qf[mt][kk] = *(const bf16x8*)(Q + (((size_t)h * 2048 + qb * 64 + mloc0 + mt * 16 + lrow) << 7) + kk * 32 + lkg * 8);

  const f32x4 fzero = {0.f, 0.f, 0.f, 0.f};
  f32x4 o[8][2];
#pragma unroll
  for (int dt = 0; dt < 8; ++dt) { o[dt][0] = fzero; o[dt][1] = fzero; }
  float m_i[2] = {-1e30f, -1e30f}, l_i[2] = {0.f, 0.f};

  const int nkb = qb + 1;
  for (int kb = 0; kb < nkb; ++kb) {
    __syncthreads();
#pragma unroll
    for (int it = 0; it < 8; ++it)
      stage16(Kb + kbase0 + ((size_t)(kb * 64 + it * 8) << 7), (char*)Ks + (tid + it * 128) * 16);
#pragma unroll
    for (int it = 0; it < 8; ++it)
      stage16(Vt + vbase0 + (size_t)it * 16 * 2048 + kb * 64, (char*)Vs + (tid + it * 128) * 16);
    asm volatile("s_waitcnt vmcnt(0)" ::: "memory");
    __syncthreads();

    // S^T = K · Q_B   (rows n, cols m)
    f32x4 s[4][2];
#pragma unroll
    for (int nt = 0; nt < 4; ++nt) { s[nt][0] = fzero; s[nt][1] = fzero; }
#pragma unroll
    for (int kk = 0; kk < 4; ++kk) {
      const int cof = ((kk * 4 + lkg) ^ sw) << 4;
      bf16x8 kf[4];
#pragma unroll
      for (int nt = 0; nt < 4; ++nt)
        kf[nt] = *(const bf16x8*)((const char*)Ks + (nt * 16 + lrow) * 256 + cof);
#pragma unroll
      for (int nt = 0; nt < 4; ++nt)
#pragma unroll
        for (int mt = 0; mt < 2; ++mt)
          s[nt][mt] = mfma16(kf[nt], qf[mt][kk], s[nt][mt]);
    }
    if (kb == qb) {  // diagonal: mask n > m (local coords)
#pragma unroll
      for (int nt = 0; nt < 4; ++nt)
#pragma unroll
        for (int mt = 0; mt < 2; ++mt) {
          int m = mloc0 + mt * 16 + lrow;
#pragma unroll
          for (int r = 0; r < 4; ++r)
            if (nt * 16 + lkg * 4 + r > m) s[nt][mt][r] = -1e30f;
        }
    }
    __syncthreads();  // all Ks reads done before P overwrites it

    // online softmax per m-tile; write P[m][n] b64 into Ks (swizzled)
    float alpha[2];
#pragma unroll
    for (int mt = 0; mt < 2; ++mt) {
      float mx = -1e30f;
#pragma unroll
      for (int nt = 0; nt < 4; ++nt)
#pragma unroll
        for (int r = 0; r < 4; ++r) mx = fmaxf(mx, s[nt][mt][r]);
      mx = fmaxf(mx, __shfl_xor(mx, 16));
      mx = fmaxf(mx, __shfl_xor(mx, 32));
      float mnew = fmaxf(m_i[mt], mx);
      alpha[mt] = fexp2(m_i[mt] - mnew);
      m_i[mt] = mnew;
      float ps = 0.f;
      const int m = mloc0 + mt * 16 + lrow;
      const int hh = lkg & 1;
#pragma unroll
      for (int nt = 0; nt < 4; ++nt) {
        u16x4 p4;
#pragma unroll
        for (int r = 0; r < 4; ++r) {
          float p = fexp2(s[nt][mt][r] - mnew);
          ps += p;
          p4[r] = f2bf(p);
        }
        int cc = 2 * nt + (lkg >> 1);
        *(u16x4*)((char*)Ks + m * 128 + ((cc ^ (m & 7)) << 4) + hh * 8) = p4;
      }
      ps += __shfl_xor(ps, 16);
      ps += __shfl_xor(ps, 32);
      l_i[mt] = l_i[mt] * alpha[mt] + ps;
    }
#pragma unroll
    for (int dt = 0; dt < 8; ++dt) {
      o[dt][0] *= alpha[0];
      o[dt][1] *= alpha[1];
    }

    // O^T += V^T · P_B
#pragma unroll
    for (int kk = 0; kk < 2; ++kk) {
      const int cof = ((kk * 4 + lkg) ^ sw) << 4;
      bf16x8 pf[2], vf[8];
#pragma unroll
      for (int mt = 0; mt < 2; ++mt) {
        int m = mloc0 + mt * 16 + lrow;
        pf[mt] = *(const bf16x8*)((const char*)Ks + m * 128 + cof);
      }
#pragma unroll
      for (int dt = 0; dt < 8; ++dt)
        vf[dt] = *(const bf16x8*)((const char*)Vs + (dt * 16 + lrow) * 128 + cof);
#pragma unroll
      for (int dt = 0; dt < 8; ++dt)
#pragma unroll
        for (int mt = 0; mt < 2; ++mt)
          o[dt][mt] = mfma16(vf[dt], pf[mt], o[dt][mt]);
    }
  }

  // epilogue: O^T -> LDS (rows m, 256B, swizzled) -> coalesced global store
  __syncthreads();
#pragma unroll
  for (int mt = 0; mt < 2; ++mt) {
    float inv = 1.f / l_i[mt];
    int m = mloc0 + mt * 16 + lrow;
    const int hh = lkg & 1;
#pragma unroll
    for (int dt = 0; dt < 8; ++dt) {
      u16x4 w4;
#pragma unroll
      for (int r = 0; r < 4; ++r) w4[r] = f2bf(o[dt][mt][r] * inv);
      int cc = 2 * dt + (lkg >> 1);
      *(u16x4*)((char*)Ks + m * 256 + ((cc ^ (m & 7)) << 4) + hh * 8) = w4;
    }
  }
  __syncthreads();
#pragma unroll
  for (int it = 0; it < 8; ++it) {
    int c = tid + it * 128;
    int row = c >> 4, cc = c & 15;
    f32x4 v = *(const f32x4*)((const char*)Ks + row * 256 + ((cc ^ (row & 7)) << 4));
    *(f32x4*)(Y + (size_t)(qb * 64 + row) * 2048 + h * 128 + cc * 8) = v;
  }
}

// ---------- launch ----------

extern "C" void kernel_launch(void* const* d_in, const int* in_sizes, int n_in,
                              void* d_out, int out_size, void* d_ws, size_t ws_size,
                              hipStream_t stream) {
  const float* x = (const float*)d_in[0];
  const float* cosp = (const float*)d_in[1];
  const float* sinp = (const float*)d_in[2];
  const float* Wq = (const float*)d_in[3];
  const float* bq = (const float*)d_in[4];
  const float* Wk = (const float*)d_in[5];
  const float* bk = (const float*)d_in[6];
  const float* Wv = (const float*)d_in[7];
  const float* bv = (const float*)d_in[8];
  const float* Wo = (const float*)d_in[9];
  float* out = (float*)d_out;
  float* out_k = out + 4194304;
  float* out_v = out + 5242880;

  char* ws = (char*)d_ws;
  u16* xb   = (u16*)(ws + 0);          //  8 MB  x  bf16
  u16* Wb   = (u16*)(ws + 8388608);    // 12 MB  fused W^T bf16 [3072][2048]
  u16* Wob  = (u16*)(ws + 20971520);   //  8 MB  Wo^T bf16
  float* qkv = (float*)(ws + 29360128);// 24 MB  raw qkv fp32 [2048][3072]
  u16* qbuf = (u16*)(ws + 54525952);   //  8 MB  q bf16 [16][2048][128]
  u16* kbuf = (u16*)(ws + 62914560);   //  2 MB  k bf16 [4][2048][128]
  u16* vtb  = (u16*)(ws + 65011712);   //  2 MB  v^T bf16 [4][128][2048]
  u16* yat  = (u16*)(ws + 67108864);   //  8 MB  attn out bf16 [2048][2048]

  yuna_convert_bf16<<<4096, 256, 0, stream>>>(x, xb, 1048576);
  yuna_transpose_bf16<<<dim3(32, 32), 256, 0, stream>>>(Wq, Wb, 2048);
  yuna_transpose_bf16<<<dim3(32, 8), 256, 0, stream>>>(Wk, Wb + (size_t)2048 * 2048, 512);
  yuna_transpose_bf16<<<dim3(32, 8), 256, 0, stream>>>(Wv, Wb + (size_t)2560 * 2048, 512);
  yuna_transpose_bf16<<<dim3(32, 32), 256, 0, stream>>>(Wo, Wob, 2048);
  yuna_gemm_bt<48><<<dim3(16, 32), 256, 0, stream>>>(xb, Wb, qkv, 2048, 3072, 2048);
  yuna_rope_scatter<<<2048, 256, 0, stream>>>(qkv, bq, bk, bv, cosp, sinp,
                                              qbuf, kbuf, out_k, out_v);
  yuna_transpose_v<<<dim3(32, 2, 4), 256, 0, stream>>>(out_v, vtb);
  yuna_flash_attn<<<dim3(16, 32), 128, 0, stream>>>(qbuf, kbuf, vtb, yat);
  yuna_gemm_bt<32><<<dim3(16, 32), 256, 0, stream>>>(yat, Wob, out, 2048, 2048, 2048);
}

// Round 3
// 267.678 us; speedup vs baseline: 1.2341x; 1.0103x over previous
//
#include <hip/hip_runtime.h>

typedef unsigned short u16;
typedef __attribute__((ext_vector_type(4))) float f32x4;
typedef __attribute__((ext_vector_type(8))) __bf16 bf16x8;
typedef __attribute__((ext_vector_type(4))) u16 u16x4;

// ---------- helpers ----------

__device__ __forceinline__ u16 f2bf(float f) {
  union { float f; unsigned u; } v; v.f = f;
  unsigned r = v.u + 0x7fffu + ((v.u >> 16) & 1u);
  return (u16)(r >> 16);
}

__device__ __forceinline__ void stage16(const void* g, void* l) {
#if __has_builtin(__builtin_amdgcn_global_load_lds)
  __builtin_amdgcn_global_load_lds((const __attribute__((address_space(1))) void*)g,
                                   (__attribute__((address_space(3))) void*)l, 16, 0, 0);
#else
  *(f32x4*)l = *(const f32x4*)g;
#endif
}

__device__ __forceinline__ f32x4 mfma16(bf16x8 a, bf16x8 b, f32x4 c) {
  return __builtin_amdgcn_mfma_f32_16x16x32_bf16(a, b, c, 0, 0, 0);
}

__device__ __forceinline__ float fexp2(float x) {
#if __has_builtin(__builtin_amdgcn_exp2f)
  return __builtin_amdgcn_exp2f(x);
#else
  return exp2f(x);
#endif
}

// rope channel select: sections [16,24,24,16,24,24] -> channels 0,1,2,0,1,2
__device__ __forceinline__ int rope_ch(int d) {
  int dd = (d < 64) ? d : d - 64;
  return (dd < 16) ? 0 : (dd < 40 ? 1 : 2);
}

// ---------- kernels ----------

__global__ void yuna_convert_bf16(const float* __restrict__ in, u16* __restrict__ out, int n4) {
  int i = blockIdx.x * blockDim.x + threadIdx.x;
  if (i < n4) {
    f32x4 v = ((const f32x4*)in)[i];
    u16x4 o;
    o.x = f2bf(v.x); o.y = f2bf(v.y); o.z = f2bf(v.z); o.w = f2bf(v.w);
    ((u16x4*)out)[i] = o;
  }
}

// fused weight transpose: out[n][k] = bf16(W[k][n]); all K=2048, ldo=2048
__global__ void yuna_prep_weights(const float* __restrict__ Wq, const float* __restrict__ Wk,
                                  const float* __restrict__ Wv, const float* __restrict__ Wo,
                                  u16* __restrict__ Wb, u16* __restrict__ Wob) {
  __shared__ float tile[64][65];
  const int mat = blockIdx.z;
  const float* W;
  u16* out;
  int N;
  if (mat == 0)      { W = Wq; out = Wb;                          N = 2048; }
  else if (mat == 1) { W = Wk; out = Wb + (size_t)2048 * 2048;    N = 512; }
  else if (mat == 2) { W = Wv; out = Wb + (size_t)2560 * 2048;    N = 512; }
  else               { W = Wo; out = Wob;                         N = 2048; }
  int k0 = blockIdx.x * 64, n0 = blockIdx.y * 64;
  if (n0 >= N) return;
  int tx = threadIdx.x & 63, ty = threadIdx.x >> 6;
#pragma unroll
  for (int j = 0; j < 64; j += 4)
    tile[ty + j][tx] = W[(size_t)(k0 + ty + j) * N + n0 + tx];
  __syncthreads();
#pragma unroll
  for (int j = 0; j < 64; j += 4)
    out[(size_t)(n0 + ty + j) * 2048 + k0 + tx] = f2bf(tile[tx][ty + j]);
}

// vtb[kvh][d][t] = bf16(pv[kvh][t][d])
__global__ void yuna_transpose_v(const float* __restrict__ pv, u16* __restrict__ vtb) {
  __shared__ float tile[64][65];
  int t0 = blockIdx.x * 64, d0 = blockIdx.y * 64, kvh = blockIdx.z;
  int tx = threadIdx.x & 63, ty = threadIdx.x >> 6;
#pragma unroll
  for (int j = 0; j < 64; j += 4)
    tile[ty + j][tx] = pv[(size_t)(kvh * 2048 + t0 + ty + j) * 128 + d0 + tx];
  __syncthreads();
#pragma unroll
  for (int j = 0; j < 64; j += 4)
    vtb[(size_t)(kvh * 128 + d0 + ty + j) * 2048 + t0 + tx] = f2bf(tile[tx][ty + j]);
}

// C[M][N] fp32 = A[M][K] bf16 @ Bt[N][K] bf16.  Tile 128 x (2*WN), BK=64.
// XOR-swizzled 16B chunks: LDS(row,c) holds global (row, c^(row&7)).
template <int WN>
__global__ __launch_bounds__(256, 2) void yuna_gemm_bt(
    const u16* __restrict__ A, const u16* __restrict__ Bt,
    float* __restrict__ C, int M, int N, int K) {
  constexpr int NF = WN / 16;
  constexpr int BROWS = 2 * WN;
  __shared__ __align__(16) u16 As[128 * 64];
  __shared__ __align__(16) u16 Bs[BROWS * 64];
  const int tid = threadIdx.x;
  const int wave = tid >> 6, lane = tid & 63;
  const int m0 = blockIdx.x * 128, n0 = blockIdx.y * (2 * WN);
  const int wr = (wave >> 1) * 64, wc = (wave & 1) * WN;
  const int lrow = lane & 15, lkg = lane >> 4;

  const int srow = tid >> 3;
  const int ssc = (tid & 7) ^ ((tid >> 3) & 7);
  const size_t abase = (size_t)(m0 + srow) * K + ssc * 8;
  const size_t bbase = (size_t)(n0 + srow) * K + ssc * 8;

  const f32x4 fzero = {0.f, 0.f, 0.f, 0.f};
  f32x4 acc[4][NF];
#pragma unroll
  for (int mi = 0; mi < 4; ++mi)
#pragma unroll
    for (int ni = 0; ni < NF; ++ni) acc[mi][ni] = fzero;

  const int sw = lrow & 7;
  for (int k0 = 0; k0 < K; k0 += 64) {
    __syncthreads();
#pragma unroll
    for (int it = 0; it < 4; ++it)
      stage16(A + abase + (size_t)it * 32 * K + k0, (char*)As + (tid + it * 256) * 16);
#pragma unroll
    for (int it = 0; it < BROWS / 32; ++it)
      stage16(Bt + bbase + (size_t)it * 32 * K + k0, (char*)Bs + (tid + it * 256) * 16);
    asm volatile("s_waitcnt vmcnt(0)" ::: "memory");
    __syncthreads();
#pragma unroll
    for (int kk = 0; kk < 2; ++kk) {
      const int cof = ((kk * 4 + lkg) ^ sw) << 4;
      bf16x8 af[4], bfr[NF];
#pragma unroll
      for (int mi = 0; mi < 4; ++mi)
        af[mi] = *(const bf16x8*)((const char*)As + (wr + mi * 16 + lrow) * 128 + cof);
#pragma unroll
      for (int ni = 0; ni < NF; ++ni)
        bfr[ni] = *(const bf16x8*)((const char*)Bs + (wc + ni * 16 + lrow) * 128 + cof);
#pragma unroll
      for (int mi = 0; mi < 4; ++mi)
#pragma unroll
        for (int ni = 0; ni < NF; ++ni)
          acc[mi][ni] = mfma16(af[mi], bfr[ni], acc[mi][ni]);
    }
  }
#pragma unroll
  for (int mi = 0; mi < 4; ++mi)
#pragma unroll
    for (int ni = 0; ni < NF; ++ni) {
      int r0 = m0 + wr + mi * 16 + lkg * 4;
      int c = n0 + wc + ni * 16 + lrow;
#pragma unroll
      for (int r = 0; r < 4; ++r)
        C[(size_t)(r0 + r) * N + c] = acc[mi][ni][r];
    }
}

// bias + multi-section rope + scatter
__global__ void yuna_rope_scatter(
    const float* __restrict__ qkv, const float* __restrict__ bq,
    const float* __restrict__ bk, const float* __restrict__ bv,
    const float* __restrict__ cosp, const float* __restrict__ sinp,
    u16* __restrict__ qb, u16* __restrict__ kb,
    float* __restrict__ pk, float* __restrict__ pv) {
  const float QSCALE = 1.4426950408889634f * 0.08838834764831845f;
  int t = blockIdx.x;
  int tid = threadIdx.x;
  const float* row = qkv + (size_t)t * 3072;
  size_t cbase = (size_t)t * 128;
  for (int i = tid; i < 1024; i += 256) {
    int h = i >> 6, d = i & 63;
    float a = row[h * 128 + d] + bq[h * 128 + d];
    float b = row[h * 128 + d + 64] + bq[h * 128 + d + 64];
    float c0 = cosp[(size_t)rope_ch(d) * 262144 + cbase + d];
    float s0 = sinp[(size_t)rope_ch(d) * 262144 + cbase + d];
    float c1 = cosp[(size_t)rope_ch(d + 64) * 262144 + cbase + d + 64];
    float s1 = sinp[(size_t)rope_ch(d + 64) * 262144 + cbase + d + 64];
    float o0 = a * c0 - b * s0;
    float o1 = b * c1 + a * s1;
    size_t o = ((size_t)h * 2048 + t) * 128 + d;
    qb[o] = f2bf(o0 * QSCALE);
    qb[o + 64] = f2bf(o1 * QSCALE);
  }
  {
    int kvh = tid >> 6, d = tid & 63;
    float a = row[2048 + kvh * 128 + d] + bk[kvh * 128 + d];
    float b = row[2048 + kvh * 128 + d + 64] + bk[kvh * 128 + d + 64];
    float c0 = cosp[(size_t)rope_ch(d) * 262144 + cbase + d];
    float s0 = sinp[(size_t)rope_ch(d) * 262144 + cbase + d];
    float c1 = cosp[(size_t)rope_ch(d + 64) * 262144 + cbase + d + 64];
    float s1 = sinp[(size_t)rope_ch(d + 64) * 262144 + cbase + d + 64];
    float o0 = a * c0 - b * s0;
    float o1 = b * c1 + a * s1;
    size_t o = ((size_t)kvh * 2048 + t) * 128 + d;
    kb[o] = f2bf(o0); kb[o + 64] = f2bf(o1);
    pk[o] = o0; pk[o + 64] = o1;
  }
  for (int i = tid; i < 512; i += 256) {
    int kvh = i >> 7, d = i & 127;
    pv[((size_t)kvh * 2048 + t) * 128 + d] = row[2560 + kvh * 128 + d] + bv[kvh * 128 + d];
  }
}

// flash attention, causal, GQA.  S^T formulation, double-buffered K/V with
// raw s_barrier + fine-grained vmcnt (prefetch stays in flight across barrier).
// block = 2 waves; wave owns 32 q-rows; BN=64 per iter.
__global__ __launch_bounds__(128, 2) void yuna_flash_attn(
    const u16* __restrict__ Q,   // [16][2048][128] pre-scaled
    const u16* __restrict__ Kb,  // [4][2048][128]
    const u16* __restrict__ Vt,  // [4][128][2048]
    u16* __restrict__ Y) {       // [2048][2048]
  __shared__ __align__(16) u16 Ks[2][64 * 128];
  __shared__ __align__(16) u16 Vs[2][128 * 64];
  __shared__ __align__(16) u16 Ps[64 * 64];
  const int h = blockIdx.x;
  const int yb = blockIdx.y;
  const int qb = (yb < 16) ? yb : 47 - yb;  // pairs (i,i+256) sum to 33 iters
  const int kvh = h >> 2;
  const int tid = threadIdx.x, wave = tid >> 6, lane = tid & 63;
  const int lrow = lane & 15, lkg = lane >> 4;
  const int mloc0 = wave * 32;
  const int sw = lrow & 7;

  const int krow = tid >> 4;
  const int ksc = (tid & 15) ^ ((tid >> 4) & 7);
  const size_t kbase0 = ((size_t)(kvh * 2048 + krow) << 7) + ksc * 8;
  const int vrow = tid >> 3;
  const int vsc = (tid & 7) ^ ((tid >> 3) & 7);
  const size_t vbase0 = (size_t)(kvh * 128 + vrow) * 2048 + vsc * 8;

  bf16x8 qf[2][4];
#pragma unroll
  for (int mt = 0; mt < 2; ++mt)
#pragma unroll
    for (int kk = 0; kk < 4; ++kk)
      qf[mt][kk] = *(const bf16x8*)(Q + (((size_t)h * 2048 + qb * 64 + mloc0 + mt * 16 + lrow) << 7) + kk * 32 + lkg * 8);

  const f32x4 fzero = {0.f, 0.f, 0.f, 0.f};
  f32x4 o[8][2];
#pragma unroll
  for (int dt = 0; dt < 8; ++dt) { o[dt][0] = fzero; o[dt][1] = fzero; }
  float m_i[2] = {-1e30f, -1e30f}, l_i[2] = {0.f, 0.f};

  const int nkb = qb + 1;

  // prologue: stage kb=0 into buffer 0  (16 loads/thread)
#pragma unroll
  for (int it = 0; it < 8; ++it)
    stage16(Kb + kbase0 + ((size_t)(it * 8) << 7), (char*)Ks[0] + (tid + it * 128) * 16);
#pragma unroll
  for (int it = 0; it < 8; ++it)
    stage16(Vt + vbase0 + (size_t)it * 16 * 2048, (char*)Vs[0] + (tid + it * 128) * 16);

  for (int kb = 0; kb < nkb; ++kb) {
    const int cur = kb & 1;
    const char* Ksb = (const char*)Ks[cur];
    const char* Vsb = (const char*)Vs[cur];
    if (kb + 1 < nkb) {
      // prefetch kb+1 into the other buffer; wait only for current tile
      char* Ksn = (char*)Ks[cur ^ 1];
      char* Vsn = (char*)Vs[cur ^ 1];
#pragma unroll
      for (int it = 0; it < 8; ++it)
        stage16(Kb + kbase0 + ((size_t)((kb + 1) * 64 + it * 8) << 7), Ksn + (tid + it * 128) * 16);
#pragma unroll
      for (int it = 0; it < 8; ++it)
        stage16(Vt + vbase0 + (size_t)it * 16 * 2048 + (kb + 1) * 64, Vsn + (tid + it * 128) * 16);
      asm volatile("s_waitcnt vmcnt(16)\n\ts_barrier" ::: "memory");
    } else {
      asm volatile("s_waitcnt vmcnt(0)\n\ts_barrier" ::: "memory");
    }

    // S^T = K · Q_B
    f32x4 s[4][2];
#pragma unroll
    for (int nt = 0; nt < 4; ++nt) { s[nt][0] = fzero; s[nt][1] = fzero; }
#pragma unroll
    for (int kk = 0; kk < 4; ++kk) {
      const int cof = ((kk * 4 + lkg) ^ sw) << 4;
      bf16x8 kf[4];
#pragma unroll
      for (int nt = 0; nt < 4; ++nt)
        kf[nt] = *(const bf16x8*)(Ksb + (nt * 16 + lrow) * 256 + cof);
#pragma unroll
      for (int nt = 0; nt < 4; ++nt)
#pragma unroll
        for (int mt = 0; mt < 2; ++mt)
          s[nt][mt] = mfma16(kf[nt], qf[mt][kk], s[nt][mt]);
    }
    if (kb == qb) {  // diagonal: mask n > m
#pragma unroll
      for (int nt = 0; nt < 4; ++nt)
#pragma unroll
        for (int mt = 0; mt < 2; ++mt) {
          int m = mloc0 + mt * 16 + lrow;
#pragma unroll
          for (int r = 0; r < 4; ++r)
            if (nt * 16 + lkg * 4 + r > m) s[nt][mt][r] = -1e30f;
        }
    }

    // online softmax; P rows are wave-private -> no barrier needed
    float alpha[2];
#pragma unroll
    for (int mt = 0; mt < 2; ++mt) {
      float mx = -1e30f;
#pragma unroll
      for (int nt = 0; nt < 4; ++nt)
#pragma unroll
        for (int r = 0; r < 4; ++r) mx = fmaxf(mx, s[nt][mt][r]);
      mx = fmaxf(mx, __shfl_xor(mx, 16));
      mx = fmaxf(mx, __shfl_xor(mx, 32));
      float mnew = fmaxf(m_i[mt], mx);
      alpha[mt] = fexp2(m_i[mt] - mnew);
      m_i[mt] = mnew;
      float ps = 0.f;
      const int m = mloc0 + mt * 16 + lrow;
      const int hh = lkg & 1;
#pragma unroll
      for (int nt = 0; nt < 4; ++nt) {
        u16x4 p4;
#pragma unroll
        for (int r = 0; r < 4; ++r) {
          float p = fexp2(s[nt][mt][r] - mnew);
          ps += p;
          p4[r] = f2bf(p);
        }
        int cc = 2 * nt + (lkg >> 1);
        *(u16x4*)((char*)Ps + m * 128 + ((cc ^ (m & 7)) << 4) + hh * 8) = p4;
      }
      ps += __shfl_xor(ps, 16);
      ps += __shfl_xor(ps, 32);
      l_i[mt] = l_i[mt] * alpha[mt] + ps;
    }
#pragma unroll
    for (int dt = 0; dt < 8; ++dt) {
      o[dt][0] *= alpha[0];
      o[dt][1] *= alpha[1];
    }

    // O^T += V^T · P_B
#pragma unroll
    for (int kk = 0; kk < 2; ++kk) {
      const int cof = ((kk * 4 + lkg) ^ sw) << 4;
      bf16x8 pf[2], vf[8];
#pragma unroll
      for (int mt = 0; mt < 2; ++mt) {
        int m = mloc0 + mt * 16 + lrow;
        pf[mt] = *(const bf16x8*)((char*)Ps + m * 128 + cof);
      }
#pragma unroll
      for (int dt = 0; dt < 8; ++dt)
        vf[dt] = *(const bf16x8*)(Vsb + (dt * 16 + lrow) * 128 + cof);
#pragma unroll
      for (int dt = 0; dt < 8; ++dt)
#pragma unroll
        for (int mt = 0; mt < 2; ++mt)
          o[dt][mt] = mfma16(vf[dt], pf[mt], o[dt][mt]);
    }
    // protect buffer cur^1 (overwritten by next iter's prefetch) + Ps reuse
    asm volatile("s_barrier" ::: "memory");
  }

  // epilogue: O^T -> LDS (reuse Ks[0]; rows m, 256B, swizzled) -> coalesced store
  __syncthreads();
#pragma unroll
  for (int mt = 0; mt < 2; ++mt) {
    float inv = 1.f / l_i[mt];
    int m = mloc0 + mt * 16 + lrow;
    const int hh = lkg & 1;
#pragma unroll
    for (int dt = 0; dt < 8; ++dt) {
      u16x4 w4;
#pragma unroll
      for (int r = 0; r < 4; ++r) w4[r] = f2bf(o[dt][mt][r] * inv);
      int cc = 2 * dt + (lkg >> 1);
      *(u16x4*)((char*)Ks[0] + m * 256 + ((cc ^ (m & 7)) << 4) + hh * 8) = w4;
    }
  }
  __syncthreads();
#pragma unroll
  for (int it = 0; it < 8; ++it) {
    int c = tid + it * 128;
    int row = c >> 4, cc = c & 15;
    f32x4 v = *(const f32x4*)((const char*)Ks[0] + row * 256 + ((cc ^ (row & 7)) << 4));
    *(f32x4*)(Y + (size_t)(qb * 64 + row) * 2048 + h * 128 + cc * 8) = v;
  }
}

// ---------- launch ----------

extern "C" void kernel_launch(void* const* d_in, const int* in_sizes, int n_in,
                              void* d_out, int out_size, void* d_ws, size_t ws_size,
                              hipStream_t stream) {
  const float* x = (const float*)d_in[0];
  const float* cosp = (const float*)d_in[1];
  const float* sinp = (const float*)d_in[2];
  const float* Wq = (const float*)d_in[3];
  const float* bq = (const float*)d_in[4];
  const float* Wk = (const float*)d_in[5];
  const float* bk = (const float*)d_in[6];
  const float* Wv = (const float*)d_in[7];
  const float* bv = (const float*)d_in[8];
  const float* Wo = (const float*)d_in[9];
  float* out = (float*)d_out;
  float* out_k = out + 4194304;
  float* out_v = out + 5242880;

  char* ws = (char*)d_ws;
  u16* xb   = (u16*)(ws + 0);          //  8 MB  x  bf16
  u16* Wb   = (u16*)(ws + 8388608);    // 12 MB  fused W^T bf16 [3072][2048]
  u16* Wob  = (u16*)(ws + 20971520);   //  8 MB  Wo^T bf16
  float* qkv = (float*)(ws + 29360128);// 24 MB  raw qkv fp32 [2048][3072]
  u16* qbuf = (u16*)(ws + 54525952);   //  8 MB  q bf16 [16][2048][128]
  u16* kbuf = (u16*)(ws + 62914560);   //  2 MB  k bf16 [4][2048][128]
  u16* vtb  = (u16*)(ws + 65011712);   //  2 MB  v^T bf16 [4][128][2048]
  u16* yat  = (u16*)(ws + 67108864);   //  8 MB  attn out bf16 [2048][2048]

  yuna_convert_bf16<<<4096, 256, 0, stream>>>(x, xb, 1048576);
  yuna_prep_weights<<<dim3(32, 32, 4), 256, 0, stream>>>(Wq, Wk, Wv, Wo, Wb, Wob);
  yuna_gemm_bt<48><<<dim3(16, 32), 256, 0, stream>>>(xb, Wb, qkv, 2048, 3072, 2048);
  yuna_rope_scatter<<<2048, 256, 0, stream>>>(qkv, bq, bk, bv, cosp, sinp,
                                              qbuf, kbuf, out_k, out_v);
  yuna_transpose_v<<<dim3(32, 2, 4), 256, 0, stream>>>(out_v, vtb);
  yuna_flash_attn<<<dim3(16, 32), 128, 0, stream>>>(qbuf, kbuf, vtb, yat);
  yuna_gemm_bt<32><<<dim3(16, 32), 256, 0, stream>>>(yat, Wob, out, 2048, 2048, 2048);
}

// Round 4
// 242.181 us; speedup vs baseline: 1.3640x; 1.1053x over previous
//
#include <hip/hip_runtime.h>

typedef unsigned short u16;
typedef unsigned int u32;
typedef __attribute__((ext_vector_type(4))) float f32x4;
typedef __attribute__((ext_vector_type(8))) __bf16 bf16x8;
typedef __attribute__((ext_vector_type(4))) u16 u16x4;
typedef __attribute__((ext_vector_type(2))) u32 u32x2;

// ---------- helpers ----------

__device__ __forceinline__ u16 f2bf(float f) {
  union { float f; unsigned u; } v; v.f = f;
  unsigned r = v.u + 0x7fffu + ((v.u >> 16) & 1u);
  return (u16)(r >> 16);
}

// pack two floats to bf16x2 (round-half-up) in 3 ops via v_perm
__device__ __forceinline__ u32 pack_bf2(float a, float b) {
  union { float f; unsigned u; } x, y;
  x.f = a; y.f = b;
#if __has_builtin(__builtin_amdgcn_perm)
  return __builtin_amdgcn_perm(y.u + 0x8000u, x.u + 0x8000u, 0x07060302u);
#else
  return (u32)((x.u + 0x8000u) >> 16) | ((y.u + 0x8000u) & 0xffff0000u);
#endif
}

__device__ __forceinline__ void stage16(const void* g, void* l) {
#if __has_builtin(__builtin_amdgcn_global_load_lds)
  __builtin_amdgcn_global_load_lds((const __attribute__((address_space(1))) void*)g,
                                   (__attribute__((address_space(3))) void*)l, 16, 0, 0);
#else
  *(f32x4*)l = *(const f32x4*)g;
#endif
}

__device__ __forceinline__ f32x4 mfma16(bf16x8 a, bf16x8 b, f32x4 c) {
  return __builtin_amdgcn_mfma_f32_16x16x32_bf16(a, b, c, 0, 0, 0);
}

__device__ __forceinline__ float fexp2(float x) {
#if __has_builtin(__builtin_amdgcn_exp2f)
  return __builtin_amdgcn_exp2f(x);
#else
  return exp2f(x);
#endif
}

// rope channel select: sections [16,24,24,16,24,24] -> channels 0,1,2,0,1,2
__device__ __forceinline__ int rope_ch(int d) {
  int dd = (d < 64) ? d : d - 64;
  return (dd < 16) ? 0 : (dd < 40 ? 1 : 2);
}

// ---------- kernels ----------

__global__ void yuna_convert_bf16(const float* __restrict__ in, u16* __restrict__ out, int n4) {
  int i = blockIdx.x * blockDim.x + threadIdx.x;
  if (i < n4) {
    f32x4 v = ((const f32x4*)in)[i];
    u16x4 o;
    o.x = f2bf(v.x); o.y = f2bf(v.y); o.z = f2bf(v.z); o.w = f2bf(v.w);
    ((u16x4*)out)[i] = o;
  }
}

// fused weight transpose: out[n][k] = bf16(W[k][n]); all K=2048, ldo=2048
__global__ void yuna_prep_weights(const float* __restrict__ Wq, const float* __restrict__ Wk,
                                  const float* __restrict__ Wv, const float* __restrict__ Wo,
                                  u16* __restrict__ Wb, u16* __restrict__ Wob) {
  __shared__ float tile[64][65];
  const int mat = blockIdx.z;
  const float* W;
  u16* out;
  int N;
  if (mat == 0)      { W = Wq; out = Wb;                          N = 2048; }
  else if (mat == 1) { W = Wk; out = Wb + (size_t)2048 * 2048;    N = 512; }
  else if (mat == 2) { W = Wv; out = Wb + (size_t)2560 * 2048;    N = 512; }
  else               { W = Wo; out = Wob;                         N = 2048; }
  int k0 = blockIdx.x * 64, n0 = blockIdx.y * 64;
  if (n0 >= N) return;
  int tx = threadIdx.x & 63, ty = threadIdx.x >> 6;
#pragma unroll
  for (int j = 0; j < 64; j += 4)
    tile[ty + j][tx] = W[(size_t)(k0 + ty + j) * N + n0 + tx];
  __syncthreads();
#pragma unroll
  for (int j = 0; j < 64; j += 4)
    out[(size_t)(n0 + ty + j) * 2048 + k0 + tx] = f2bf(tile[tx][ty + j]);
}

// vtb[kvh][d][t] = bf16(pv[kvh][t][d])
__global__ void yuna_transpose_v(const float* __restrict__ pv, u16* __restrict__ vtb) {
  __shared__ float tile[64][65];
  int t0 = blockIdx.x * 64, d0 = blockIdx.y * 64, kvh = blockIdx.z;
  int tx = threadIdx.x & 63, ty = threadIdx.x >> 6;
#pragma unroll
  for (int j = 0; j < 64; j += 4)
    tile[ty + j][tx] = pv[(size_t)(kvh * 2048 + t0 + ty + j) * 128 + d0 + tx];
  __syncthreads();
#pragma unroll
  for (int j = 0; j < 64; j += 4)
    vtb[(size_t)(kvh * 128 + d0 + ty + j) * 2048 + t0 + tx] = f2bf(tile[tx][ty + j]);
}

// C[M][N] fp32 = A[M][K] bf16 @ Bt[N][K] bf16.  Tile 128 x (2*WN), BK=64.
// XOR-swizzled 16B chunks: LDS(row,c) holds global (row, c^(row&7)).
template <int WN>
__global__ __launch_bounds__(256, 2) void yuna_gemm_bt(
    const u16* __restrict__ A, const u16* __restrict__ Bt,
    float* __restrict__ C, int M, int N, int K) {
  constexpr int NF = WN / 16;
  constexpr int BROWS = 2 * WN;
  __shared__ __align__(16) u16 As[128 * 64];
  __shared__ __align__(16) u16 Bs[BROWS * 64];
  const int tid = threadIdx.x;
  const int wave = tid >> 6, lane = tid & 63;
  const int m0 = blockIdx.x * 128, n0 = blockIdx.y * (2 * WN);
  const int wr = (wave >> 1) * 64, wc = (wave & 1) * WN;
  const int lrow = lane & 15, lkg = lane >> 4;

  const int srow = tid >> 3;
  const int ssc = (tid & 7) ^ ((tid >> 3) & 7);
  const size_t abase = (size_t)(m0 + srow) * K + ssc * 8;
  const size_t bbase = (size_t)(n0 + srow) * K + ssc * 8;

  const f32x4 fzero = {0.f, 0.f, 0.f, 0.f};
  f32x4 acc[4][NF];
#pragma unroll
  for (int mi = 0; mi < 4; ++mi)
#pragma unroll
    for (int ni = 0; ni < NF; ++ni) acc[mi][ni] = fzero;

  const int sw = lrow & 7;
  for (int k0 = 0; k0 < K; k0 += 64) {
    __syncthreads();
#pragma unroll
    for (int it = 0; it < 4; ++it)
      stage16(A + abase + (size_t)it * 32 * K + k0, (char*)As + (tid + it * 256) * 16);
#pragma unroll
    for (int it = 0; it < BROWS / 32; ++it)
      stage16(Bt + bbase + (size_t)it * 32 * K + k0, (char*)Bs + (tid + it * 256) * 16);
    asm volatile("s_waitcnt vmcnt(0)" ::: "memory");
    __syncthreads();
#pragma unroll
    for (int kk = 0; kk < 2; ++kk) {
      const int cof = ((kk * 4 + lkg) ^ sw) << 4;
      bf16x8 af[4], bfr[NF];
#pragma unroll
      for (int mi = 0; mi < 4; ++mi)
        af[mi] = *(const bf16x8*)((const char*)As + (wr + mi * 16 + lrow) * 128 + cof);
#pragma unroll
      for (int ni = 0; ni < NF; ++ni)
        bfr[ni] = *(const bf16x8*)((const char*)Bs + (wc + ni * 16 + lrow) * 128 + cof);
#pragma unroll
      for (int mi = 0; mi < 4; ++mi)
#pragma unroll
        for (int ni = 0; ni < NF; ++ni)
          acc[mi][ni] = mfma16(af[mi], bfr[ni], acc[mi][ni]);
    }
  }
#pragma unroll
  for (int mi = 0; mi < 4; ++mi)
#pragma unroll
    for (int ni = 0; ni < NF; ++ni) {
      int r0 = m0 + wr + mi * 16 + lkg * 4;
      int c = n0 + wc + ni * 16 + lrow;
#pragma unroll
      for (int r = 0; r < 4; ++r)
        C[(size_t)(r0 + r) * N + c] = acc[mi][ni][r];
    }
}

// bias + multi-section rope + scatter
__global__ void yuna_rope_scatter(
    const float* __restrict__ qkv, const float* __restrict__ bq,
    const float* __restrict__ bk, const float* __restrict__ bv,
    const float* __restrict__ cosp, const float* __restrict__ sinp,
    u16* __restrict__ qb, u16* __restrict__ kb,
    float* __restrict__ pk, float* __restrict__ pv) {
  const float QSCALE = 1.4426950408889634f * 0.08838834764831845f;
  int t = blockIdx.x;
  int tid = threadIdx.x;
  const float* row = qkv + (size_t)t * 3072;
  size_t cbase = (size_t)t * 128;
  for (int i = tid; i < 1024; i += 256) {
    int h = i >> 6, d = i & 63;
    float a = row[h * 128 + d] + bq[h * 128 + d];
    float b = row[h * 128 + d + 64] + bq[h * 128 + d + 64];
    float c0 = cosp[(size_t)rope_ch(d) * 262144 + cbase + d];
    float s0 = sinp[(size_t)rope_ch(d) * 262144 + cbase + d];
    float c1 = cosp[(size_t)rope_ch(d + 64) * 262144 + cbase + d + 64];
    float s1 = sinp[(size_t)rope_ch(d + 64) * 262144 + cbase + d + 64];
    float o0 = a * c0 - b * s0;
    float o1 = b * c1 + a * s1;
    size_t o = ((size_t)h * 2048 + t) * 128 + d;
    qb[o] = f2bf(o0 * QSCALE);
    qb[o + 64] = f2bf(o1 * QSCALE);
  }
  {
    int kvh = tid >> 6, d = tid & 63;
    float a = row[2048 + kvh * 128 + d] + bk[kvh * 128 + d];
    float b = row[2048 + kvh * 128 + d + 64] + bk[kvh * 128 + d + 64];
    float c0 = cosp[(size_t)rope_ch(d) * 262144 + cbase + d];
    float s0 = sinp[(size_t)rope_ch(d) * 262144 + cbase + d];
    float c1 = cosp[(size_t)rope_ch(d + 64) * 262144 + cbase + d + 64];
    float s1 = sinp[(size_t)rope_ch(d + 64) * 262144 + cbase + d + 64];
    float o0 = a * c0 - b * s0;
    float o1 = b * c1 + a * s1;
    size_t o = ((size_t)kvh * 2048 + t) * 128 + d;
    kb[o] = f2bf(o0); kb[o + 64] = f2bf(o1);
    pk[o] = o0; pk[o + 64] = o1;
  }
  for (int i = tid; i < 512; i += 256) {
    int kvh = i >> 7, d = i & 127;
    pv[((size_t)kvh * 2048 + t) * 128 + d] = row[2560 + kvh * 128 + d] + bv[kvh * 128 + d];
  }
}

// flash attention, causal, GQA.  S^T formulation.
// block = 4 waves (256 thr); each wave owns 16 q-rows (TLP: 2048 waves total,
// 2 waves/SIMD).  BN=64/iter, double-buffered K/V, raw s_barrier + vmcnt(8).
__global__ __launch_bounds__(256, 2) void yuna_flash_attn(
    const u16* __restrict__ Q,   // [16][2048][128] pre-scaled
    const u16* __restrict__ Kb,  // [4][2048][128]
    const u16* __restrict__ Vt,  // [4][128][2048]
    u16* __restrict__ Y) {       // [2048][2048]
  __shared__ __align__(16) u16 Ks[2][64 * 128];
  __shared__ __align__(16) u16 Vs[2][128 * 64];
  __shared__ __align__(16) u16 Ps[64 * 64];
  const int h = blockIdx.x;
  const int yb = blockIdx.y;
  const int qb = (yb < 16) ? yb : 47 - yb;  // pairs (i,i+256) sum to 33 iters
  const int kvh = h >> 2;
  const int tid = threadIdx.x, wave = tid >> 6, lane = tid & 63;
  const int lrow = lane & 15, lkg = lane >> 4;
  const int m = wave * 16 + lrow;   // this wave's local q-row (0..63)
  const int sw = lrow & 7;

  // staging: K tile 64x128 (1024 chunks), V tile 128x64 (1024 chunks); 4 each/thread
  const int krow = tid >> 4;                        // +16/iter (=0 mod 8: it-invariant swizzle)
  const int ksc = (tid & 15) ^ ((tid >> 4) & 7);
  const size_t kbase0 = ((size_t)(kvh * 2048 + krow) << 7) + ksc * 8;
  const int vrow = tid >> 3;                        // +32/iter
  const int vsc = (tid & 7) ^ ((tid >> 3) & 7);
  const size_t vbase0 = (size_t)(kvh * 128 + vrow) * 2048 + vsc * 8;

  bf16x8 qf[4];
#pragma unroll
  for (int kk = 0; kk < 4; ++kk)
    qf[kk] = *(const bf16x8*)(Q + (((size_t)h * 2048 + qb * 64 + m) << 7) + kk * 32 + lkg * 8);

  const f32x4 fzero = {0.f, 0.f, 0.f, 0.f};
  f32x4 o[8];
#pragma unroll
  for (int dt = 0; dt < 8; ++dt) o[dt] = fzero;
  float m_i = -1e30f, l_i = 0.f;

  const int nkb = qb + 1;

  // prologue: stage kb=0 into buffer 0 (8 loads/thread)
#pragma unroll
  for (int it = 0; it < 4; ++it)
    stage16(Kb + kbase0 + ((size_t)(it * 16) << 7), (char*)Ks[0] + (tid + it * 256) * 16);
#pragma unroll
  for (int it = 0; it < 4; ++it)
    stage16(Vt + vbase0 + (size_t)it * 32 * 2048, (char*)Vs[0] + (tid + it * 256) * 16);

  for (int kb = 0; kb < nkb; ++kb) {
    const int cur = kb & 1;
    const char* Ksb = (const char*)Ks[cur];
    const char* Vsb = (const char*)Vs[cur];
    if (kb + 1 < nkb) {
      char* Ksn = (char*)Ks[cur ^ 1];
      char* Vsn = (char*)Vs[cur ^ 1];
#pragma unroll
      for (int it = 0; it < 4; ++it)
        stage16(Kb + kbase0 + ((size_t)((kb + 1) * 64 + it * 16) << 7), Ksn + (tid + it * 256) * 16);
#pragma unroll
      for (int it = 0; it < 4; ++it)
        stage16(Vt + vbase0 + (size_t)it * 32 * 2048 + (kb + 1) * 64, Vsn + (tid + it * 256) * 16);
      asm volatile("s_waitcnt vmcnt(8)\n\ts_barrier" ::: "memory");
    } else {
      asm volatile("s_waitcnt vmcnt(0)\n\ts_barrier" ::: "memory");
    }

    // S^T = K · Q_B  (D: col=lane&15 -> q-row m, row=lkg*4+r -> kv-row n)
    f32x4 s[4];
#pragma unroll
    for (int nt = 0; nt < 4; ++nt) s[nt] = fzero;
#pragma unroll
    for (int kk = 0; kk < 4; ++kk) {
      const int cof = ((kk * 4 + lkg) ^ sw) << 4;
      bf16x8 kf[4];
#pragma unroll
      for (int nt = 0; nt < 4; ++nt)
        kf[nt] = *(const bf16x8*)(Ksb + (nt * 16 + lrow) * 256 + cof);
#pragma unroll
      for (int nt = 0; nt < 4; ++nt)
        s[nt] = mfma16(kf[nt], qf[kk], s[nt]);
    }
    if (kb == qb) {  // diagonal: mask n > m
#pragma unroll
      for (int nt = 0; nt < 4; ++nt)
#pragma unroll
        for (int r = 0; r < 4; ++r)
          if (nt * 16 + lkg * 4 + r > m) s[nt][r] = -1e30f;
    }

    // online softmax (16 rows/wave); P rows wave-private
    float mx = -1e30f;
#pragma unroll
    for (int nt = 0; nt < 4; ++nt)
#pragma unroll
      for (int r = 0; r < 4; ++r) mx = fmaxf(mx, s[nt][r]);
    mx = fmaxf(mx, __shfl_xor(mx, 16));
    mx = fmaxf(mx, __shfl_xor(mx, 32));
    float mnew = fmaxf(m_i, mx);
    float alpha = fexp2(m_i - mnew);
    m_i = mnew;
    float ps = 0.f;
    const int hh = lkg & 1;
#pragma unroll
    for (int nt = 0; nt < 4; ++nt) {
      float p0 = fexp2(s[nt][0] - mnew);
      float p1 = fexp2(s[nt][1] - mnew);
      float p2 = fexp2(s[nt][2] - mnew);
      float p3 = fexp2(s[nt][3] - mnew);
      ps += (p0 + p1) + (p2 + p3);
      u32x2 pk2;
      pk2.x = pack_bf2(p0, p1);
      pk2.y = pack_bf2(p2, p3);
      int cc = 2 * nt + (lkg >> 1);
      *(u32x2*)((char*)Ps + m * 128 + ((cc ^ (m & 7)) << 4) + hh * 8) = pk2;
    }
    ps += __shfl_xor(ps, 16);
    ps += __shfl_xor(ps, 32);
    l_i = l_i * alpha + ps;
#pragma unroll
    for (int dt = 0; dt < 8; ++dt) o[dt] *= alpha;

    // O^T += V^T · P_B  (B frag: col=lane&15 -> m, k -> n; wave-private Ps rows)
#pragma unroll
    for (int kk = 0; kk < 2; ++kk) {
      const int cof = ((kk * 4 + lkg) ^ sw) << 4;
      bf16x8 pf = *(const bf16x8*)((char*)Ps + m * 128 + cof);
      bf16x8 vf[8];
#pragma unroll
      for (int dt = 0; dt < 8; ++dt)
        vf[dt] = *(const bf16x8*)(Vsb + (dt * 16 + lrow) * 128 + cof);
#pragma unroll
      for (int dt = 0; dt < 8; ++dt)
        o[dt] = mfma16(vf[dt], pf, o[dt]);
    }
    // protect buffer cur^1 before next iter's prefetch overwrites it
    asm volatile("s_barrier" ::: "memory");
  }

  // epilogue: O^T -> LDS (reuse Ks[0]; 64 rows x 256B, swizzled) -> coalesced store
  __syncthreads();
  {
    float inv = 1.f / l_i;
    const int hh = lkg & 1;
#pragma unroll
    for (int dt = 0; dt < 8; ++dt) {
      u32x2 w2;
      w2.x = pack_bf2(o[dt][0] * inv, o[dt][1] * inv);
      w2.y = pack_bf2(o[dt][2] * inv, o[dt][3] * inv);
      int cc = 2 * dt + (lkg >> 1);
      *(u32x2*)((char*)Ks[0] + m * 256 + ((cc ^ (m & 7)) << 4) + hh * 8) = w2;
    }
  }
  __syncthreads();
#pragma unroll
  for (int it = 0; it < 4; ++it) {
    int c = tid + it * 256;
    int row = c >> 4, cc = c & 15;
    f32x4 v = *(const f32x4*)((const char*)Ks[0] + row * 256 + ((cc ^ (row & 7)) << 4));
    *(f32x4*)(Y + (size_t)(qb * 64 + row) * 2048 + h * 128 + cc * 8) = v;
  }
}

// ---------- launch ----------

extern "C" void kernel_launch(void* const* d_in, const int* in_sizes, int n_in,
                              void* d_out, int out_size, void* d_ws, size_t ws_size,
                              hipStream_t stream) {
  const float* x = (const float*)d_in[0];
  const float* cosp = (const float*)d_in[1];
  const float* sinp = (const float*)d_in[2];
  const float* Wq = (const float*)d_in[3];
  const float* bq = (const float*)d_in[4];
  const float* Wk = (const float*)d_in[5];
  const float* bk = (const float*)d_in[6];
  const float* Wv = (const float*)d_in[7];
  const float* bv = (const float*)d_in[8];
  const float* Wo = (const float*)d_in[9];
  float* out = (float*)d_out;
  float* out_k = out + 4194304;
  float* out_v = out + 5242880;

  char* ws = (char*)d_ws;
  u16* xb   = (u16*)(ws + 0);          //  8 MB  x  bf16
  u16* Wb   = (u16*)(ws + 8388608);    // 12 MB  fused W^T bf16 [3072][2048]
  u16* Wob  = (u16*)(ws + 20971520);   //  8 MB  Wo^T bf16
  float* qkv = (float*)(ws + 29360128);// 24 MB  raw qkv fp32 [2048][3072]
  u16* qbuf = (u16*)(ws + 54525952);   //  8 MB  q bf16 [16][2048][128]
  u16* kbuf = (u16*)(ws + 62914560);   //  2 MB  k bf16 [4][2048][128]
  u16* vtb  = (u16*)(ws + 65011712);   //  2 MB  v^T bf16 [4][128][2048]
  u16* yat  = (u16*)(ws + 67108864);   //  8 MB  attn out bf16 [2048][2048]

  yuna_convert_bf16<<<4096, 256, 0, stream>>>(x, xb, 1048576);
  yuna_prep_weights<<<dim3(32, 32, 4), 256, 0, stream>>>(Wq, Wk, Wv, Wo, Wb, Wob);
  yuna_gemm_bt<48><<<dim3(16, 32), 256, 0, stream>>>(xb, Wb, qkv, 2048, 3072, 2048);
  yuna_rope_scatter<<<2048, 256, 0, stream>>>(qkv, bq, bk, bv, cosp, sinp,
                                              qbuf, kbuf, out_k, out_v);
  yuna_transpose_v<<<dim3(32, 2, 4), 256, 0, stream>>>(out_v, vtb);
  yuna_flash_attn<<<dim3(16, 32), 256, 0, stream>>>(qbuf, kbuf, vtb, yat);
  yuna_gemm_bt<32><<<dim3(16, 32), 256, 0, stream>>>(yat, Wob, out, 2048, 2048, 2048);
}

// Round 6
// 227.028 us; speedup vs baseline: 1.4550x; 1.0667x over previous
//
#include <hip/hip_runtime.h>

typedef unsigned short u16;
typedef unsigned int u32;
typedef __attribute__((ext_vector_type(4))) float f32x4;
typedef __attribute__((ext_vector_type(8))) __bf16 bf16x8;
typedef __attribute__((ext_vector_type(4))) u16 u16x4;
typedef __attribute__((ext_vector_type(2))) u32 u32x2;

// ---------- helpers ----------

__device__ __forceinline__ u16 f2bf(float f) {
  union { float f; unsigned u; } v; v.f = f;
  unsigned r = v.u + 0x7fffu + ((v.u >> 16) & 1u);
  return (u16)(r >> 16);
}

// pack two floats to bf16x2 (round-half-up) via v_perm
__device__ __forceinline__ u32 pack_bf2(float a, float b) {
  union { float f; unsigned u; } x, y;
  x.f = a; y.f = b;
#if __has_builtin(__builtin_amdgcn_perm)
  return __builtin_amdgcn_perm(y.u + 0x8000u, x.u + 0x8000u, 0x07060302u);
#else
  return (u32)((x.u + 0x8000u) >> 16) | ((y.u + 0x8000u) & 0xffff0000u);
#endif
}

__device__ __forceinline__ void stage16(const void* g, void* l) {
#if __has_builtin(__builtin_amdgcn_global_load_lds)
  __builtin_amdgcn_global_load_lds((const __attribute__((address_space(1))) void*)g,
                                   (__attribute__((address_space(3))) void*)l, 16, 0, 0);
#else
  *(f32x4*)l = *(const f32x4*)g;
#endif
}

__device__ __forceinline__ f32x4 mfma16(bf16x8 a, bf16x8 b, f32x4 c) {
  return __builtin_amdgcn_mfma_f32_16x16x32_bf16(a, b, c, 0, 0, 0);
}

__device__ __forceinline__ float fexp2(float x) {
#if __has_builtin(__builtin_amdgcn_exp2f)
  return __builtin_amdgcn_exp2f(x);
#else
  return exp2f(x);
#endif
}

// rope channel select: sections [16,24,24,16,24,24] -> channels 0,1,2,0,1,2
__device__ __forceinline__ int rope_ch(int d) {
  int dd = (d < 64) ? d : d - 64;
  return (dd < 16) ? 0 : (dd < 40 ? 1 : 2);
}

// ---------- kernels ----------

// blocks < 4096: x fp32 -> bf16.  blocks >= 4096: build channel-selected
// rope tables csel/ssel[t][d] = cos/sin[ch(d)][t][d]  (2048x128 each).
__global__ void yuna_convert_prep(const float* __restrict__ in, u16* __restrict__ out,
                                  const float* __restrict__ cosp, const float* __restrict__ sinp,
                                  float* __restrict__ csel, float* __restrict__ ssel) {
  int b = blockIdx.x;
  if (b < 4096) {
    int i = b * 256 + threadIdx.x;
    f32x4 v = ((const f32x4*)in)[i];
    u16x4 o;
    o.x = f2bf(v.x); o.y = f2bf(v.y); o.z = f2bf(v.z); o.w = f2bf(v.w);
    ((u16x4*)out)[i] = o;
  } else {
    int i = (b - 4096) * 256 + threadIdx.x;  // 0..65535, 4 elems each
    int i4 = i * 4;
    int t = i4 >> 7, d = i4 & 127;
    f32x4 c, s;
#pragma unroll
    for (int j = 0; j < 4; ++j) {
      int ch = rope_ch(d + j);
      c[j] = cosp[(size_t)ch * 262144 + (size_t)t * 128 + d + j];
      s[j] = sinp[(size_t)ch * 262144 + (size_t)t * 128 + d + j];
    }
    ((f32x4*)csel)[i] = c;
    ((f32x4*)ssel)[i] = s;
  }
}

// fused weight transpose: out[n][k] = bf16(W[k][n]); all K=2048, ldo=2048
__global__ void yuna_prep_weights(const float* __restrict__ Wq, const float* __restrict__ Wk,
                                  const float* __restrict__ Wv, const float* __restrict__ Wo,
                                  u16* __restrict__ Wb, u16* __restrict__ Wob) {
  __shared__ float tile[64][65];
  const int mat = blockIdx.z;
  const float* W;
  u16* out;
  int N;
  if (mat == 0)      { W = Wq; out = Wb;                          N = 2048; }
  else if (mat == 1) { W = Wk; out = Wb + (size_t)2048 * 2048;    N = 512; }
  else if (mat == 2) { W = Wv; out = Wb + (size_t)2560 * 2048;    N = 512; }
  else               { W = Wo; out = Wob;                         N = 2048; }
  int k0 = blockIdx.x * 64, n0 = blockIdx.y * 64;
  if (n0 >= N) return;
  int tx = threadIdx.x & 63, ty = threadIdx.x >> 6;
#pragma unroll
  for (int j = 0; j < 64; j += 4)
    tile[ty + j][tx] = W[(size_t)(k0 + ty + j) * N + n0 + tx];
  __syncthreads();
#pragma unroll
  for (int j = 0; j < 64; j += 4)
    out[(size_t)(n0 + ty + j) * 2048 + k0 + tx] = f2bf(tile[tx][ty + j]);
}

// Fused QKV GEMM + bias + rope + scatter.
// A [2048][2048] bf16 (x), Bt [3072][2048] bf16 (W^T fused).
// Tile 64x128, BK=64, double-buffered, raw s_barrier + vmcnt(6).
// Column mapping: wave w owns cols {w*16..w*16+15} u {w*16+64..w*16+79}
// (ni=0 -> d, ni=1 -> d+64): rope pair lives in one lane's registers.
// by<16 -> Q head, 16..19 -> K head, 20..23 -> V head.
__global__ __launch_bounds__(256, 3) void yuna_gemm_qkv(
    const u16* __restrict__ A, const u16* __restrict__ Bt,
    const float* __restrict__ bq, const float* __restrict__ bk, const float* __restrict__ bv,
    const float* __restrict__ csel, const float* __restrict__ ssel,
    u16* __restrict__ qb, u16* __restrict__ kb, u16* __restrict__ vtb,
    float* __restrict__ pk, float* __restrict__ pv) {
  const int K = 2048;
  __shared__ __align__(16) char smem[49152];  // As[2]:16K @0, Bs[2]:32K @16K
  const int tid = threadIdx.x;
  const int wave = tid >> 6, lane = tid & 63;
  const int lrow = lane & 15, lkg = lane >> 4;
  const int m0 = blockIdx.x * 64;
  const int by = blockIdx.y;
  const int n0 = by * 128;
  const int sw = lrow & 7;

  const int srow = tid >> 3;
  const int ssc = (tid & 7) ^ ((tid >> 3) & 7);
  const size_t abase = (size_t)(m0 + srow) * K + ssc * 8;
  const size_t bbase = (size_t)(n0 + srow) * K + ssc * 8;

  const f32x4 fzero = {0.f, 0.f, 0.f, 0.f};
  f32x4 acc[4][2];
#pragma unroll
  for (int mi = 0; mi < 4; ++mi) { acc[mi][0] = fzero; acc[mi][1] = fzero; }

  // prologue: stage k-tile 0 into buffer 0 (6 loads/thread)
#pragma unroll
  for (int it = 0; it < 2; ++it)
    stage16(A + abase + (size_t)it * 32 * K, smem + (tid + it * 256) * 16);
#pragma unroll
  for (int it = 0; it < 4; ++it)
    stage16(Bt + bbase + (size_t)it * 32 * K, smem + 16384 + (tid + it * 256) * 16);

  for (int k0 = 0, ki = 0; k0 < K; k0 += 64, ++ki) {
    const int cur = ki & 1;
    const char* Asb = smem + cur * 8192;
    const char* Bsb = smem + 16384 + cur * 16384;
    if (k0 + 64 < K) {
      char* Asn = smem + (cur ^ 1) * 8192;
      char* Bsn = smem + 16384 + (cur ^ 1) * 16384;
#pragma unroll
      for (int it = 0; it < 2; ++it)
        stage16(A + abase + (size_t)it * 32 * K + k0 + 64, Asn + (tid + it * 256) * 16);
#pragma unroll
      for (int it = 0; it < 4; ++it)
        stage16(Bt + bbase + (size_t)it * 32 * K + k0 + 64, Bsn + (tid + it * 256) * 16);
      asm volatile("s_waitcnt vmcnt(6)\n\ts_barrier" ::: "memory");
    } else {
      asm volatile("s_waitcnt vmcnt(0)\n\ts_barrier" ::: "memory");
    }
#pragma unroll
    for (int kk = 0; kk < 2; ++kk) {
      const int cof = ((kk * 4 + lkg) ^ sw) << 4;
      bf16x8 af[4], bfr[2];
#pragma unroll
      for (int mi = 0; mi < 4; ++mi)
        af[mi] = *(const bf16x8*)(Asb + (mi * 16 + lrow) * 128 + cof);
#pragma unroll
      for (int ni = 0; ni < 2; ++ni)
        bfr[ni] = *(const bf16x8*)(Bsb + (wave * 16 + ni * 64 + lrow) * 128 + cof);
#pragma unroll
      for (int mi = 0; mi < 4; ++mi)
#pragma unroll
        for (int ni = 0; ni < 2; ++ni)
          acc[mi][ni] = mfma16(af[mi], bfr[ni], acc[mi][ni]);
    }
    asm volatile("s_barrier" ::: "memory");
  }

  // ---- epilogue ----  acc[mi][ni][r]: t = m0+mi*16+lkg*4+r, d = wave*16+ni*64+lrow
  if (by >= 20) {
    // V: bias, write pv fp32 [kvh][t][d] + vtb bf16 [kvh][d][t] (4 t's packed)
    const int kvh = by - 20;
#pragma unroll
    for (int mi = 0; mi < 4; ++mi)
#pragma unroll
      for (int ni = 0; ni < 2; ++ni) {
        int d = wave * 16 + ni * 64 + lrow;
        float bb = bv[kvh * 128 + d];
        int mb = mi * 16 + lkg * 4;
        float v0 = acc[mi][ni][0] + bb, v1 = acc[mi][ni][1] + bb;
        float v2 = acc[mi][ni][2] + bb, v3 = acc[mi][ni][3] + bb;
        size_t pb = ((size_t)(kvh * 2048 + m0 + mb)) * 128 + d;
        pv[pb] = v0; pv[pb + 128] = v1; pv[pb + 256] = v2; pv[pb + 384] = v3;
        u16x4 w;
        w.x = f2bf(v0); w.y = f2bf(v1); w.z = f2bf(v2); w.w = f2bf(v3);
        *(u16x4*)(vtb + ((size_t)(kvh * 128 + d)) * 2048 + m0 + mb) = w;
      }
  } else {
    // Q/K: rope entirely in registers (acc[mi][0] = chan d, acc[mi][1] = chan d+64)
    const float QSCALE = 1.4426950408889634f * 0.08838834764831845f;
    const bool isQ = (by < 16);
    const int h = isQ ? by : (by - 16);
    const float* bias = isQ ? bq : bk;
    const int dlo = wave * 16 + lrow;
    const float blo = bias[h * 128 + dlo];
    const float bhi = bias[h * 128 + dlo + 64];
#pragma unroll
    for (int mi = 0; mi < 4; ++mi) {
      const int tb = m0 + mi * 16 + lkg * 4;
#pragma unroll
      for (int r = 0; r < 4; ++r) {
        const int t = tb + r;
        float a = acc[mi][0][r] + blo;
        float b = acc[mi][1][r] + bhi;
        size_t cb = (size_t)t * 128 + dlo;
        float cl = csel[cb], sl = ssel[cb];
        float ch = csel[cb + 64], sh = ssel[cb + 64];
        float lo = a * cl - b * sl;
        float hi = b * ch + a * sh;
        size_t o = (((size_t)(h * 2048 + t)) << 7) + dlo;
        if (isQ) {
          qb[o] = f2bf(lo * QSCALE);
          qb[o + 64] = f2bf(hi * QSCALE);
        } else {
          kb[o] = f2bf(lo);
          kb[o + 64] = f2bf(hi);
          pk[o] = lo; pk[o + 64] = hi;
        }
      }
    }
  }
}

// Output GEMM: C[2048][2048] fp32 = A(yat) @ Wob^T.  Same pipelined structure.
__global__ __launch_bounds__(256, 3) void yuna_gemm_out(
    const u16* __restrict__ A, const u16* __restrict__ Bt, float* __restrict__ C) {
  const int K = 2048;
  __shared__ __align__(16) char smem[49152];
  const int tid = threadIdx.x;
  const int wave = tid >> 6, lane = tid & 63;
  const int lrow = lane & 15, lkg = lane >> 4;
  const int m0 = blockIdx.x * 64;
  const int n0 = blockIdx.y * 128;
  const int wc = wave * 32;
  const int sw = lrow & 7;

  const int srow = tid >> 3;
  const int ssc = (tid & 7) ^ ((tid >> 3) & 7);
  const size_t abase = (size_t)(m0 + srow) * K + ssc * 8;
  const size_t bbase = (size_t)(n0 + srow) * K + ssc * 8;

  const f32x4 fzero = {0.f, 0.f, 0.f, 0.f};
  f32x4 acc[4][2];
#pragma unroll
  for (int mi = 0; mi < 4; ++mi) { acc[mi][0] = fzero; acc[mi][1] = fzero; }

#pragma unroll
  for (int it = 0; it < 2; ++it)
    stage16(A + abase + (size_t)it * 32 * K, smem + (tid + it * 256) * 16);
#pragma unroll
  for (int it = 0; it < 4; ++it)
    stage16(Bt + bbase + (size_t)it * 32 * K, smem + 16384 + (tid + it * 256) * 16);

  for (int k0 = 0, ki = 0; k0 < K; k0 += 64, ++ki) {
    const int cur = ki & 1;
    const char* Asb = smem + cur * 8192;
    const char* Bsb = smem + 16384 + cur * 16384;
    if (k0 + 64 < K) {
      char* Asn = smem + (cur ^ 1) * 8192;
      char* Bsn = smem + 16384 + (cur ^ 1) * 16384;
#pragma unroll
      for (int it = 0; it < 2; ++it)
        stage16(A + abase + (size_t)it * 32 * K + k0 + 64, Asn + (tid + it * 256) * 16);
#pragma unroll
      for (int it = 0; it < 4; ++it)
        stage16(Bt + bbase + (size_t)it * 32 * K + k0 + 64, Bsn + (tid + it * 256) * 16);
      asm volatile("s_waitcnt vmcnt(6)\n\ts_barrier" ::: "memory");
    } else {
      asm volatile("s_waitcnt vmcnt(0)\n\ts_barrier" ::: "memory");
    }
#pragma unroll
    for (int kk = 0; kk < 2; ++kk) {
      const int cof = ((kk * 4 + lkg) ^ sw) << 4;
      bf16x8 af[4], bfr[2];
#pragma unroll
      for (int mi = 0; mi < 4; ++mi)
        af[mi] = *(const bf16x8*)(Asb + (mi * 16 + lrow) * 128 + cof);
#pragma unroll
      for (int ni = 0; ni < 2; ++ni)
        bfr[ni] = *(const bf16x8*)(Bsb + (wc + ni * 16 + lrow) * 128 + cof);
#pragma unroll
      for (int mi = 0; mi < 4; ++mi)
#pragma unroll
        for (int ni = 0; ni < 2; ++ni)
          acc[mi][ni] = mfma16(af[mi], bfr[ni], acc[mi][ni]);
    }
    asm volatile("s_barrier" ::: "memory");
  }
#pragma unroll
  for (int mi = 0; mi < 4; ++mi)
#pragma unroll
    for (int ni = 0; ni < 2; ++ni) {
      int d = wc + ni * 16 + lrow;
      int mb = mi * 16 + lkg * 4;
#pragma unroll
      for (int r = 0; r < 4; ++r)
        C[(size_t)(m0 + mb + r) * 2048 + n0 + d] = acc[mi][ni][r];
    }
}

// flash attention, causal, GQA.  S^T formulation.  (unchanged from R4)
__global__ __launch_bounds__(256, 2) void yuna_flash_attn(
    const u16* __restrict__ Q,   // [16][2048][128] pre-scaled
    const u16* __restrict__ Kb,  // [4][2048][128]
    const u16* __restrict__ Vt,  // [4][128][2048]
    u16* __restrict__ Y) {       // [2048][2048]
  __shared__ __align__(16) u16 Ks[2][64 * 128];
  __shared__ __align__(16) u16 Vs[2][128 * 64];
  __shared__ __align__(16) u16 Ps[64 * 64];
  const int h = blockIdx.x;
  const int yb = blockIdx.y;
  const int qb = (yb < 16) ? yb : 47 - yb;
  const int kvh = h >> 2;
  const int tid = threadIdx.x, wave = tid >> 6, lane = tid & 63;
  const int lrow = lane & 15, lkg = lane >> 4;
  const int m = wave * 16 + lrow;
  const int sw = lrow & 7;

  const int krow = tid >> 4;
  const int ksc = (tid & 15) ^ ((tid >> 4) & 7);
  const size_t kbase0 = ((size_t)(kvh * 2048 + krow) << 7) + ksc * 8;
  const int vrow = tid >> 3;
  const int vsc = (tid & 7) ^ ((tid >> 3) & 7);
  const size_t vbase0 = (size_t)(kvh * 128 + vrow) * 2048 + vsc * 8;

  bf16x8 qf[4];
#pragma unroll
  for (int kk = 0; kk < 4; ++kk)
    qf[kk] = *(const bf16x8*)(Q + (((size_t)h * 2048 + qb * 64 + m) << 7) + kk * 32 + lkg * 8);

  const f32x4 fzero = {0.f, 0.f, 0.f, 0.f};
  f32x4 o[8];
#pragma unroll
  for (int dt = 0; dt < 8; ++dt) o[dt] = fzero;
  float m_i = -1e30f, l_i = 0.f;

  const int nkb = qb + 1;

#pragma unroll
  for (int it = 0; it < 4; ++it)
    stage16(Kb + kbase0 + ((size_t)(it * 16) << 7), (char*)Ks[0] + (tid + it * 256) * 16);
#pragma unroll
  for (int it = 0; it < 4; ++it)
    stage16(Vt + vbase0 + (size_t)it * 32 * 2048, (char*)Vs[0] + (tid + it * 256) * 16);

  for (int kb = 0; kb < nkb; ++kb) {
    const int cur = kb & 1;
    const char* Ksb = (const char*)Ks[cur];
    const char* Vsb = (const char*)Vs[cur];
    if (kb + 1 < nkb) {
      char* Ksn = (char*)Ks[cur ^ 1];
      char* Vsn = (char*)Vs[cur ^ 1];
#pragma unroll
      for (int it = 0; it < 4; ++it)
        stage16(Kb + kbase0 + ((size_t)((kb + 1) * 64 + it * 16) << 7), Ksn + (tid + it * 256) * 16);
#pragma unroll
      for (int it = 0; it < 4; ++it)
        stage16(Vt + vbase0 + (size_t)it * 32 * 2048 + (kb + 1) * 64, Vsn + (tid + it * 256) * 16);
      asm volatile("s_waitcnt vmcnt(8)\n\ts_barrier" ::: "memory");
    } else {
      asm volatile("s_waitcnt vmcnt(0)\n\ts_barrier" ::: "memory");
    }

    f32x4 s[4];
#pragma unroll
    for (int nt = 0; nt < 4; ++nt) s[nt] = fzero;
#pragma unroll
    for (int kk = 0; kk < 4; ++kk) {
      const int cof = ((kk * 4 + lkg) ^ sw) << 4;
      bf16x8 kf[4];
#pragma unroll
      for (int nt = 0; nt < 4; ++nt)
        kf[nt] = *(const bf16x8*)(Ksb + (nt * 16 + lrow) * 256 + cof);
#pragma unroll
      for (int nt = 0; nt < 4; ++nt)
        s[nt] = mfma16(kf[nt], qf[kk], s[nt]);
    }
    if (kb == qb) {
#pragma unroll
      for (int nt = 0; nt < 4; ++nt)
#pragma unroll
        for (int r = 0; r < 4; ++r)
          if (nt * 16 + lkg * 4 + r > m) s[nt][r] = -1e30f;
    }

    float mx = -1e30f;
#pragma unroll
    for (int nt = 0; nt < 4; ++nt)
#pragma unroll
      for (int r = 0; r < 4; ++r) mx = fmaxf(mx, s[nt][r]);
    mx = fmaxf(mx, __shfl_xor(mx, 16));
    mx = fmaxf(mx, __shfl_xor(mx, 32));
    float mnew = fmaxf(m_i, mx);
    float alpha = fexp2(m_i - mnew);
    m_i = mnew;
    float ps = 0.f;
    const int hh = lkg & 1;
#pragma unroll
    for (int nt = 0; nt < 4; ++nt) {
      float p0 = fexp2(s[nt][0] - mnew);
      float p1 = fexp2(s[nt][1] - mnew);
      float p2 = fexp2(s[nt][2] - mnew);
      float p3 = fexp2(s[nt][3] - mnew);
      ps += (p0 + p1) + (p2 + p3);
      u32x2 pk2;
      pk2.x = pack_bf2(p0, p1);
      pk2.y = pack_bf2(p2, p3);
      int cc = 2 * nt + (lkg >> 1);
      *(u32x2*)((char*)Ps + m * 128 + ((cc ^ (m & 7)) << 4) + hh * 8) = pk2;
    }
    ps += __shfl_xor(ps, 16);
    ps += __shfl_xor(ps, 32);
    l_i = l_i * alpha + ps;
#pragma unroll
    for (int dt = 0; dt < 8; ++dt) o[dt] *= alpha;

#pragma unroll
    for (int kk = 0; kk < 2; ++kk) {
      const int cof = ((kk * 4 + lkg) ^ sw) << 4;
      bf16x8 pf = *(const bf16x8*)((char*)Ps + m * 128 + cof);
      bf16x8 vf[8];
#pragma unroll
      for (int dt = 0; dt < 8; ++dt)
        vf[dt] = *(const bf16x8*)(Vsb + (dt * 16 + lrow) * 128 + cof);
#pragma unroll
      for (int dt = 0; dt < 8; ++dt)
        o[dt] = mfma16(vf[dt], pf, o[dt]);
    }
    asm volatile("s_barrier" ::: "memory");
  }

  __syncthreads();
  {
    float inv = 1.f / l_i;
    const int hh = lkg & 1;
#pragma unroll
    for (int dt = 0; dt < 8; ++dt) {
      u32x2 w2;
      w2.x = pack_bf2(o[dt][0] * inv, o[dt][1] * inv);
      w2.y = pack_bf2(o[dt][2] * inv, o[dt][3] * inv);
      int cc = 2 * dt + (lkg >> 1);
      *(u32x2*)((char*)Ks[0] + m * 256 + ((cc ^ (m & 7)) << 4) + hh * 8) = w2;
    }
  }
  __syncthreads();
#pragma unroll
  for (int it = 0; it < 4; ++it) {
    int c = tid + it * 256;
    int row = c >> 4, cc = c & 15;
    f32x4 v = *(const f32x4*)((const char*)Ks[0] + row * 256 + ((cc ^ (row & 7)) << 4));
    *(f32x4*)(Y + (size_t)(qb * 64 + row) * 2048 + h * 128 + cc * 8) = v;
  }
}

// ---------- launch ----------

extern "C" void kernel_launch(void* const* d_in, const int* in_sizes, int n_in,
                              void* d_out, int out_size, void* d_ws, size_t ws_size,
                              hipStream_t stream) {
  const float* x = (const float*)d_in[0];
  const float* cosp = (const float*)d_in[1];
  const float* sinp = (const float*)d_in[2];
  const float* Wq = (const float*)d_in[3];
  const float* bq = (const float*)d_in[4];
  const float* Wk = (const float*)d_in[5];
  const float* bk = (const float*)d_in[6];
  const float* Wv = (const float*)d_in[7];
  const float* bv = (const float*)d_in[8];
  const float* Wo = (const float*)d_in[9];
  float* out = (float*)d_out;
  float* out_k = out + 4194304;
  float* out_v = out + 5242880;

  char* ws = (char*)d_ws;
  u16* xb   = (u16*)(ws + 0);          //  8 MB  x  bf16
  u16* Wb   = (u16*)(ws + 8388608);    // 12 MB  fused W^T bf16 [3072][2048]
  u16* Wob  = (u16*)(ws + 20971520);   //  8 MB  Wo^T bf16
  float* csel = (float*)(ws + 29360128); // 1 MB rope cos table [2048][128]
  float* ssel = (float*)(ws + 30408704); // 1 MB rope sin table
  u16* qbuf = (u16*)(ws + 54525952);   //  8 MB  q bf16 [16][2048][128]
  u16* kbuf = (u16*)(ws + 62914560);   //  2 MB  k bf16 [4][2048][128]
  u16* vtb  = (u16*)(ws + 65011712);   //  2 MB  v^T bf16 [4][128][2048]
  u16* yat  = (u16*)(ws + 67108864);   //  8 MB  attn out bf16 [2048][2048]

  yuna_convert_prep<<<4352, 256, 0, stream>>>(x, xb, cosp, sinp, csel, ssel);
  yuna_prep_weights<<<dim3(32, 32, 4), 256, 0, stream>>>(Wq, Wk, Wv, Wo, Wb, Wob);
  yuna_gemm_qkv<<<dim3(32, 24), 256, 0, stream>>>(xb, Wb, bq, bk, bv, csel, ssel,
                                                  qbuf, kbuf, vtb, out_k, out_v);
  yuna_flash_attn<<<dim3(16, 32), 256, 0, stream>>>(qbuf, kbuf, vtb, yat);
  yuna_gemm_out<<<dim3(32, 16), 256, 0, stream>>>(yat, Wob, out);
}